// Round 2
// baseline (115.374 us; speedup 1.0000x reference)
//
#include <hip/hip_runtime.h>
#include <hip/hip_bf16.h>
#include <math.h>

#define B_ 8
#define H_ 128
#define N_ 64
#define L_ 8192
#define MCH 64                 // chunk length
#define SCH (L_ / MCH)         // 128 chunks per sequence
#define EROW 136               // EBUF row stride (bf16 elems): 272 B, 16B-aligned

typedef __attribute__((ext_vector_type(8))) short bf16x8;  // MFMA A/B frag (4 VGPR)
typedef __attribute__((ext_vector_type(4))) float f32x4;   // MFMA C/D frag / NT vec

__device__ __forceinline__ float bf2f(ushort s) { return __uint_as_float(((uint)s) << 16); }
// packed RNE fp32x2 -> bf16x2 (v_cvt_pk_bf16_f32 on gfx950)
__device__ __forceinline__ uint packbf2(float a, float b) {
    __hip_bfloat162 h = __float22bfloat162_rn(make_float2(a, b));
    union { __hip_bfloat162 h2; uint u; } cv; cv.h2 = h;
    return cv.u;
}
__device__ __forceinline__ bf16x8 pack_bf8(f32x4 a, f32x4 b) {
    union { uint u[4]; bf16x8 v; } r;
    r.u[0] = packbf2(a[0], a[1]); r.u[1] = packbf2(a[2], a[3]);
    r.u[2] = packbf2(b[0], b[1]); r.u[3] = packbf2(b[2], b[3]);
    return r.v;
}

// ===================== P0: build per-head T, P, Q, r^M ======================
// 2 blocks per head (grid = 256, full GPU): block e owns column-half
// [32e, 32e+32) of T/Q and row-half of P. The K[d] mode-sum needs all 64
// modes so both halves recompute it (cheap). All emitted values are
// bit-identical to the single-block version.
__global__ __launch_bounds__(256) void s4d_build(
    const float* __restrict__ A_re, const float* __restrict__ A_im,
    const float* __restrict__ C, const float* __restrict__ D,
    const float* __restrict__ log_delta,
    ushort* __restrict__ wsT, ushort* __restrict__ wsP,
    ushort* __restrict__ wsQ, float2* __restrict__ wsRM)
{
    __shared__ float kpart[64][65];
    __shared__ float kv[64];
    __shared__ uint  pbuf[32 * 68];

    const int h = blockIdx.x >> 1;
    const int e = blockIdx.x & 1;        // column-half this block owns
    const int tid = threadIdx.x;
    const int n = tid & 63;
    const int g = tid >> 6;

    float are = fminf(A_re[h * N_ + n], -1e-4f);
    float aim = A_im[h * N_ + n];
    float step = expf(log_delta[h]);
    float dre = step * are, dim = step * aim;
    // precise r (feeds w and the scan multiplier chain)
    float er = expf(dre);
    float sd, cd; sincosf(dim, &sd, &cd);
    float rre = er * cd;
    float rim = er * sd;
    float cre = C[(h * N_ + n) * 2 + 0];
    float cim = C[(h * N_ + n) * 2 + 1];
    float inv  = 1.0f / (are * are + aim * aim);
    float numr = rre - 1.0f, numi = rim;
    float consr = (numr * are + numi * aim) * inv;
    float consi = (numi * are - numr * aim) * inv;
    float wr = cre * consr - cim * consi;
    float wi = cre * consi + cim * consr;
    float dval = D[h];

    // fast power: hardware transcendentals (~15 instr vs ~150 libm)
    auto rp = [&](float d, float& pr, float& pi) {
        float ex = __expf(d * dre);
        float ang = d * dim;
        float s = __sinf(ang), c2 = __cosf(ang);
        pr = ex * c2; pi = ex * s;
    };

    // ---- K[d] = Re(sum_n w r^d): full 64 d in both half-blocks ----
#pragma unroll
    for (int j = 0; j < 16; ++j) {
        int d = g * 16 + j;
        float pr, pi; rp((float)d, pr, pi);
        kpart[d][n] = wr * pr - wi * pi;
    }
    __syncthreads();
    if (tid < 64) {
        float s = 0.f;
#pragma unroll
        for (int m = 0; m < 64; ++m) s += kpart[tid][m];
        kv[tid] = s;
    }
    __syncthreads();

    // ---- T row n, cols [32e + 8g, +8): K[n-t] + D on diag ----
    {
        uint tw[4];
#pragma unroll
        for (int i = 0; i < 4; ++i) {
            int t0 = e * 32 + g * 8 + 2 * i, t1 = t0 + 1;
            float v0 = (t0 <= n) ? kv[n - t0] : 0.f;
            float v1 = (t1 <= n) ? kv[n - t1] : 0.f;
            if (t0 == n) v0 += dval;
            if (t1 == n) v1 += dval;
            tw[i] = packbf2(v0, v1);
        }
        *(uint4*)(wsT + ((size_t)h * 64 + n) * 64 + e * 32 + g * 8) = *(uint4*)tw;
    }

    // ---- Q rows 2n (Re), 2n+1 (Im), cols [32e + 8g, +8): r^{63-t} ----
    {
        uint qr[4], qi[4];
#pragma unroll
        for (int i = 0; i < 4; ++i) {
            int t0 = e * 32 + g * 8 + 2 * i;
            float ar0, ai0, ar1, ai1;
            rp((float)(63 - t0), ar0, ai0);
            rp((float)(62 - t0), ar1, ai1);
            qr[i] = packbf2(ar0, ar1);
            qi[i] = packbf2(ai0, ai1);
        }
        *(uint4*)(wsQ + ((size_t)h * 128 + 2 * n    ) * 64 + e * 32 + g * 8) = *(uint4*)qr;
        *(uint4*)(wsQ + ((size_t)h * 128 + 2 * n + 1) * 64 + e * 32 + g * 8) = *(uint4*)qi;
    }

    // ---- P rows j in [32e, 32e+32): [2n]=Re(w r^{j+1}), [2n+1]=-Im ----
#pragma unroll
    for (int i = 0; i < 8; ++i) {
        int jl = g * 8 + i;
        int j = e * 32 + jl;
        float pr, pi; rp((float)(j + 1), pr, pi);
        float ur = wr * pr - wi * pi;
        float ui = wr * pi + wi * pr;
        pbuf[jl * 68 + n] = packbf2(ur, -ui);
    }
    if (tid < 64) {
        // precise r^64: 6 squarings of the precise r (both halves write same)
        float mr = rre, mi = rim;
#pragma unroll
        for (int k = 0; k < 6; ++k) { float tr = mr*mr - mi*mi, ti = 2.f*mr*mi; mr = tr; mi = ti; }
        wsRM[h * 64 + n] = make_float2(mr, mi);
    }
    __syncthreads();
    {
        const int rw = tid & 31, cc = tid >> 5;   // 32 rows x 8 col-chunks
        const uint* src = &pbuf[rw * 68 + cc * 8];
        uint4* dP = (uint4*)(wsP + ((size_t)h * 64 + e * 32 + rw) * 128 + cc * 16);
        dP[0] = *(const uint4*)(src);
        dP[1] = *(const uint4*)(src + 4);
    }
}

// ===================== main: per-(b,h) fused A/B/C ==========================
__global__ __launch_bounds__(256, 4) void s4d_main(
    const float* __restrict__ x,
    const ushort* __restrict__ wsT, const ushort* __restrict__ wsP,
    const ushort* __restrict__ wsQ, const float2* __restrict__ wsRM,
    float* __restrict__ out)
{
    __shared__ ushort EBUF[SCH * EROW];          // 128 x 136 bf16 = 34.8 KB
    __shared__ float segr[4][64], segi[4][64];   // 2 KB

    const int seq = blockIdx.x;              // b*H + h; all b's of head h share an XCD
    const int h   = seq % H_;
    const int tid = threadIdx.x;
    const int w   = tid >> 6;                // wave 0..3 -> col-tiles 2w, 2w+1
    const int lane = tid & 63;
    const int n16 = lane & 15, q = lane >> 4;

    const float* xs = x + (size_t)seq * L_;

    // ---- X B-frags (nontemporal: stream-once, keep L2 for T/P/Q) ----
    bf16x8 xb[2][2];
#pragma unroll
    for (int ic = 0; ic < 2; ++ic) {
        int c = (2 * w + ic) * 16 + n16;     // chunk index = GEMM column
#pragma unroll
        for (int kc = 0; kc < 2; ++kc) {
            const float* p = xs + c * MCH + kc * 32 + q * 8;
            f32x4 f0 = __builtin_nontemporal_load((const f32x4*)p);
            f32x4 f1 = __builtin_nontemporal_load((const f32x4*)p + 1);
            xb[ic][kc] = pack_bf8(f0, f1);
        }
    }

    // ---- Phase A: E = Q * X ----
    const ushort* Qh = wsQ + (size_t)h * 128 * 64;
#pragma unroll
    for (int rt = 0; rt < 8; ++rt) {
        bf16x8 a0 = *(const bf16x8*)(Qh + ((size_t)(rt * 16 + n16)) * 64 +      q * 8);
        bf16x8 a1 = *(const bf16x8*)(Qh + ((size_t)(rt * 16 + n16)) * 64 + 32 + q * 8);
#pragma unroll
        for (int ic = 0; ic < 2; ++ic) {
            f32x4 acc = {0.f, 0.f, 0.f, 0.f};
            acc = __builtin_amdgcn_mfma_f32_16x16x32_bf16(a0, xb[ic][0], acc, 0, 0, 0);
            acc = __builtin_amdgcn_mfma_f32_16x16x32_bf16(a1, xb[ic][1], acc, 0, 0, 0);
            int c = (2 * w + ic) * 16 + n16;
            uint2 st = make_uint2(packbf2(acc[0], acc[1]), packbf2(acc[2], acc[3]));
            *(uint2*)&EBUF[c * EROW + rt * 16 + q * 4] = st;
        }
    }

    // ---- Hoisted T*X: independent of the scan; fills barrier-wait slack
    //      and removes T-load + 2 MFMAs from the post-scan critical path.
    const ushort* Th = wsT + (size_t)h * 64 * 64;
    f32x4 accT[4][2];
#pragma unroll
    for (int rt = 0; rt < 4; ++rt) {
        bf16x8 t0 = *(const bf16x8*)(Th + ((size_t)(rt * 16 + n16)) * 64 +      q * 8);
        bf16x8 t1 = *(const bf16x8*)(Th + ((size_t)(rt * 16 + n16)) * 64 + 32 + q * 8);
#pragma unroll
        for (int ic = 0; ic < 2; ++ic) {
            f32x4 a = {0.f, 0.f, 0.f, 0.f};
            a = __builtin_amdgcn_mfma_f32_16x16x32_bf16(t0, xb[ic][0], a, 0, 0, 0);
            a = __builtin_amdgcn_mfma_f32_16x16x32_bf16(t1, xb[ic][1], a, 0, 0, 0);
            accT[rt][ic] = a;
        }
    }
    __syncthreads();

    // ---- Phase B: segmented exclusive chunk scan, all 256 threads ----
    {
        const int nB = tid & 63, gB = tid >> 6;
        float2 rm = wsRM[h * 64 + nB];
        float mr = rm.x, mi = rm.y;
        float m32r = mr, m32i = mi;          // r^2048 via 5 squarings
#pragma unroll
        for (int k = 0; k < 5; ++k) {
            float tr = m32r * m32r - m32i * m32i, ti = 2.f * m32r * m32i;
            m32r = tr; m32i = ti;
        }
        float sr = 0.f, si = 0.f;            // pass 1: zero-init segment end
#pragma unroll
        for (int j = 0; j < 32; ++j) {
            uint e = *(const uint*)&EBUF[(gB * 32 + j) * EROW + 2 * nB];
            float er2 = bf2f((ushort)(e & 0xffffu)), ei2 = bf2f((ushort)(e >> 16));
            float nr = er2 + mr * sr - mi * si;
            float ni = ei2 + mr * si + mi * sr;
            sr = nr; si = ni;
        }
        segr[gB][nB] = sr; segi[gB][nB] = si;
        __syncthreads();
        float pr2 = 0.f, pi2 = 0.f;          // exclusive prefix over segments
        for (int gp = 0; gp < gB; ++gp) {
            float Er = segr[gp][nB], Ei = segi[gp][nB];
            float nr = Er + m32r * pr2 - m32i * pi2;
            float ni = Ei + m32r * pi2 + m32i * pr2;
            pr2 = nr; pi2 = ni;
        }
        sr = pr2; si = pi2;                  // pass 2: replay, write SV in place
#pragma unroll
        for (int j = 0; j < 32; ++j) {
            uint* ep = (uint*)&EBUF[(gB * 32 + j) * EROW + 2 * nB];
            uint e = *ep;
            float er2 = bf2f((ushort)(e & 0xffffu)), ei2 = bf2f((ushort)(e >> 16));
            *ep = packbf2(sr, si);
            float nr = er2 + mr * sr - mi * si;
            float ni = ei2 + mr * si + mi * sr;
            sr = nr; si = ni;
        }
    }

    // prefetch rt=0 P frags: issue before the barrier so L2 latency hides
    const ushort* Ph = wsP + (size_t)h * 64 * 128;
    bf16x8 pf0 = *(const bf16x8*)(Ph + (size_t)n16 * 128 +       q * 8);
    bf16x8 pf1 = *(const bf16x8*)(Ph + (size_t)n16 * 128 +  32 + q * 8);
    bf16x8 pf2 = *(const bf16x8*)(Ph + (size_t)n16 * 128 +  64 + q * 8);
    bf16x8 pf3 = *(const bf16x8*)(Ph + (size_t)n16 * 128 +  96 + q * 8);
    __syncthreads();

    // ---- Phase C: OUT = accT + P*SV ----
    float* op = out + (size_t)seq * L_;
#pragma unroll
    for (int rt = 0; rt < 4; ++rt) {
        bf16x8 p0, p1, p2, p3;
        if (rt == 0) { p0 = pf0; p1 = pf1; p2 = pf2; p3 = pf3; }
        else {
            p0 = *(const bf16x8*)(Ph + ((size_t)(rt * 16 + n16)) * 128 +       q * 8);
            p1 = *(const bf16x8*)(Ph + ((size_t)(rt * 16 + n16)) * 128 +  32 + q * 8);
            p2 = *(const bf16x8*)(Ph + ((size_t)(rt * 16 + n16)) * 128 +  64 + q * 8);
            p3 = *(const bf16x8*)(Ph + ((size_t)(rt * 16 + n16)) * 128 +  96 + q * 8);
        }
#pragma unroll
        for (int ic = 0; ic < 2; ++ic) {
            int c = (2 * w + ic) * 16 + n16;
            f32x4 accP = {0.f, 0.f, 0.f, 0.f};
            accP = __builtin_amdgcn_mfma_f32_16x16x32_bf16(p0,
                       *(const bf16x8*)&EBUF[c * EROW +       q * 8], accP, 0, 0, 0);
            accP = __builtin_amdgcn_mfma_f32_16x16x32_bf16(p1,
                       *(const bf16x8*)&EBUF[c * EROW +  32 + q * 8], accP, 0, 0, 0);
            accP = __builtin_amdgcn_mfma_f32_16x16x32_bf16(p2,
                       *(const bf16x8*)&EBUF[c * EROW +  64 + q * 8], accP, 0, 0, 0);
            accP = __builtin_amdgcn_mfma_f32_16x16x32_bf16(p3,
                       *(const bf16x8*)&EBUF[c * EROW +  96 + q * 8], accP, 0, 0, 0);
            f32x4 o;
            o[0] = accT[rt][ic][0] + accP[0];
            o[1] = accT[rt][ic][1] + accP[1];
            o[2] = accT[rt][ic][2] + accP[2];
            o[3] = accT[rt][ic][3] + accP[3];
            __builtin_nontemporal_store(o, (f32x4*)(op + c * MCH + rt * 16 + q * 4));
        }
    }
}

extern "C" void kernel_launch(void* const* d_in, const int* in_sizes, int n_in,
                              void* d_out, int out_size, void* d_ws, size_t ws_size,
                              hipStream_t stream)
{
    const float* x  = (const float*)d_in[0];
    const float* Ar = (const float*)d_in[1];
    const float* Ai = (const float*)d_in[2];
    const float* C  = (const float*)d_in[3];
    const float* D  = (const float*)d_in[4];
    const float* ld = (const float*)d_in[5];
    float* out = (float*)d_out;

    ushort* wsT = (ushort*)d_ws;                 // 128*64*64   bf16 = 1 MB
    ushort* wsP = wsT + (size_t)128 * 64 * 64;   // 128*64*128  bf16 = 2 MB
    ushort* wsQ = wsP + (size_t)128 * 64 * 128;  // 128*128*64  bf16 = 2 MB
    float2* wsRM = (float2*)(wsQ + (size_t)128 * 128 * 64);  // 64 KB

    hipLaunchKernelGGL(s4d_build, dim3(H_ * 2), dim3(256), 0, stream,
                       Ar, Ai, C, D, ld, wsT, wsP, wsQ, wsRM);
    hipLaunchKernelGGL(s4d_main, dim3(B_ * H_), dim3(256), 0, stream,
                       x, wsT, wsP, wsQ, wsRM, out);
}

// Round 4
// 112.906 us; speedup vs baseline: 1.0219x; 1.0219x over previous
//
#include <hip/hip_runtime.h>
#include <hip/hip_bf16.h>
#include <math.h>

#define B_ 8
#define H_ 128
#define N_ 64
#define L_ 8192
#define MCH 64                 // chunk length
#define SCH (L_ / MCH)         // 128 chunks per sequence
#define EROW 136               // EBUF row stride (bf16 elems): 272 B, 16B-aligned

// ---- LDS layout (byte offsets), phase-aliased ----
// [0, 34816)          EBUF 128x136 bf16   (pre-Phase-A: aliased by kpart 64x65 f32 = 16640 B)
// [34816, 51200)      TBL 16 KB: T (8 KB) -> Q (16 KB) -> P (16 KB), sequential lifetimes
// [51200, 53248)      seg: segr[4][64], segi[4][64] f32
// [53248, 53504)      kv[64] f32
// total 53504 B -> 3 blocks/CU (160 KiB LDS)
#define LDS_TBL   34816
#define LDS_SEG   51200
#define LDS_KV    53248
#define LDS_TOTAL 53504

typedef __attribute__((ext_vector_type(8))) short bf16x8;  // MFMA A/B frag (4 VGPR)
typedef __attribute__((ext_vector_type(4))) float f32x4;   // MFMA C/D frag / NT vec

__device__ __forceinline__ float bf2f(ushort s) { return __uint_as_float(((uint)s) << 16); }
// packed RNE fp32x2 -> bf16x2 (v_cvt_pk_bf16_f32 on gfx950)
__device__ __forceinline__ uint packbf2(float a, float b) {
    __hip_bfloat162 h = __float22bfloat162_rn(make_float2(a, b));
    union { __hip_bfloat162 h2; uint u; } cv; cv.h2 = h;
    return cv.u;
}
__device__ __forceinline__ bf16x8 pack_bf8(f32x4 a, f32x4 b) {
    union { uint u[4]; bf16x8 v; } r;
    r.u[0] = packbf2(a[0], a[1]); r.u[1] = packbf2(a[2], a[3]);
    r.u[2] = packbf2(b[0], b[1]); r.u[3] = packbf2(b[2], b[3]);
    return r.v;
}

// ============ single fused kernel: per-(b,h) build + A/B/C ============
// Tables are built per block into LDS (XOR-swizzled: byte ^= (row&7)<<4 so
// stride-128B/256B row reads hit 8 distinct 16B bank slots = wave64 b128
// bandwidth floor). Build transcendentals overlap the x HBM load latency.
__global__ __launch_bounds__(256, 3) void s4d_fused(
    const float* __restrict__ x,
    const float* __restrict__ A_re, const float* __restrict__ A_im,
    const float* __restrict__ Cp, const float* __restrict__ Dp,
    const float* __restrict__ log_delta,
    float* __restrict__ out)
{
    __shared__ __align__(16) char lds[LDS_TOTAL];
    ushort* EBUF  = (ushort*)lds;
    float*  kpart = (float*)lds;                  // [64][65], aliases EBUF pre-A
    char*   TBLb  = lds + LDS_TBL;
    float*  segr  = (float*)(lds + LDS_SEG);      // [4][64]
    float*  segi  = segr + 256;
    float*  kv    = (float*)(lds + LDS_KV);

    const int seq = blockIdx.x;              // b*H + h
    const int h   = seq % H_;
    const int tid = threadIdx.x;
    const int w   = tid >> 6;                // wave 0..3 -> col-tiles 2w, 2w+1
    const int lane = tid & 63;
    const int n16 = lane & 15, q = lane >> 4;
    const int n = tid & 63;                  // mode index (build + scan)
    const int g = tid >> 6;                  // == w

    // ---- per-mode parameters (expression-identical to old build kernel) ----
    float are = fminf(A_re[h * N_ + n], -1e-4f);
    float aim = A_im[h * N_ + n];
    float step = expf(log_delta[h]);
    float dre = step * are, dim = step * aim;
    float er = expf(dre);                    // precise r (feeds w + scan chain)
    float sd, cd; sincosf(dim, &sd, &cd);
    float rre = er * cd, rim = er * sd;
    float cre = Cp[(h * N_ + n) * 2 + 0];
    float cim = Cp[(h * N_ + n) * 2 + 1];
    float inv  = 1.0f / (are * are + aim * aim);
    float numr = rre - 1.0f, numi = rim;
    float consr = (numr * are + numi * aim) * inv;
    float consi = (numi * are - numr * aim) * inv;
    float wr = cre * consr - cim * consi;
    float wi = cre * consi + cim * consr;
    float dval = Dp[h];
    // precise r^64: 6 squarings (feeds the fp32 chunk scan)
    float m64r = rre, m64i = rim;
#pragma unroll
    for (int k = 0; k < 6; ++k) { float tr = m64r*m64r - m64i*m64i, ti = 2.f*m64r*m64i; m64r = tr; m64i = ti; }

    // fast power: hardware transcendentals (bf16-rounded outputs)
    auto rp = [&](float d, float& pr, float& pi) {
        float ex = __expf(d * dre);
        float ang = d * dim;
        float s = __sinf(ang), c2 = __cosf(ang);
        pr = ex * c2; pi = ex * s;
    };

    // ---- X loads (NT) + bf16 pack: issue first, latency hides under build ----
    const float* xs = x + (size_t)seq * L_;
    bf16x8 xbv[2][2];
#pragma unroll
    for (int ic = 0; ic < 2; ++ic) {
        int c = (2 * w + ic) * 16 + n16;
#pragma unroll
        for (int kc = 0; kc < 2; ++kc) {
            const float* p = xs + c * MCH + kc * 32 + q * 8;
            f32x4 f0 = __builtin_nontemporal_load((const f32x4*)p);
            f32x4 f1 = __builtin_nontemporal_load((const f32x4*)p + 1);
            xbv[ic][kc] = pack_bf8(f0, f1);
        }
    }

    // ---- kpart[d][n] = Re(w r^d)  (aliases EBUF; EBUF unused yet) ----
#pragma unroll
    for (int j = 0; j < 16; ++j) {
        int d = g * 16 + j;
        float pr, pi; rp((float)d, pr, pi);
        kpart[d * 65 + n] = wr * pr - wi * pi;
    }
    __syncthreads();                                           // B1
    if (tid < 64) {
        float s = 0.f;
#pragma unroll
        for (int m = 0; m < 64; ++m) s += kpart[tid * 65 + m];
        kv[tid] = s;
    }
    __syncthreads();                                           // B2

    // ---- T build: row n, cols [16g,16g+16), swizzled ----
    {
        uint tw[8];
#pragma unroll
        for (int i = 0; i < 8; ++i) {
            int t0 = g * 16 + 2 * i, t1 = t0 + 1;
            float v0 = (t0 <= n) ? kv[n - t0] : 0.f;
            float v1 = (t1 <= n) ? kv[n - t1] : 0.f;
            if (t0 == n) v0 += dval;
            if (t1 == n) v1 += dval;
            tw[i] = packbf2(v0, v1);
        }
        const uint xt = (uint)(n & 7) << 4;
        *(uint4*)(TBLb + ((n * 128 + g * 32     ) ^ xt)) = ((uint4*)tw)[0];
        *(uint4*)(TBLb + ((n * 128 + g * 32 + 16) ^ xt)) = ((uint4*)tw)[1];
    }
    __syncthreads();                                           // B3

    // ---- hoisted T*X (accT regs; T read swizzled) ----
    const uint xr = (uint)(n16 & 7) << 4;
    f32x4 accT[4][2];
#pragma unroll
    for (int rt = 0; rt < 4; ++rt) {
        int row = rt * 16 + n16;
        bf16x8 t0 = *(const bf16x8*)(TBLb + ((row * 128      + q * 16) ^ xr));
        bf16x8 t1 = *(const bf16x8*)(TBLb + ((row * 128 + 64 + q * 16) ^ xr));
#pragma unroll
        for (int ic = 0; ic < 2; ++ic) {
            f32x4 a = {0.f, 0.f, 0.f, 0.f};
            a = __builtin_amdgcn_mfma_f32_16x16x32_bf16(t0, xbv[ic][0], a, 0, 0, 0);
            a = __builtin_amdgcn_mfma_f32_16x16x32_bf16(t1, xbv[ic][1], a, 0, 0, 0);
            accT[rt][ic] = a;
        }
    }
    __syncthreads();                                           // B4 (T dead)

    // ---- Q build: rows 2n,2n+1, cols [16g,+16), swizzled (overwrites T) ----
    {
        uint qr[8], qi[8];
#pragma unroll
        for (int i = 0; i < 8; ++i) {
            int t0 = g * 16 + 2 * i;
            float ar0, ai0, ar1, ai1;
            rp((float)(63 - t0), ar0, ai0);
            rp((float)(62 - t0), ar1, ai1);
            qr[i] = packbf2(ar0, ar1);
            qi[i] = packbf2(ai0, ai1);
        }
        const int ra = 2 * n, rb = 2 * n + 1;
        const uint xa = (uint)(ra & 7) << 4, xbm = (uint)(rb & 7) << 4;
        *(uint4*)(TBLb + ((ra * 128 + g * 32     ) ^ xa)) = ((uint4*)qr)[0];
        *(uint4*)(TBLb + ((ra * 128 + g * 32 + 16) ^ xa)) = ((uint4*)qr)[1];
        *(uint4*)(TBLb + ((rb * 128 + g * 32     ) ^ xbm)) = ((uint4*)qi)[0];
        *(uint4*)(TBLb + ((rb * 128 + g * 32 + 16) ^ xbm)) = ((uint4*)qi)[1];
    }
    __syncthreads();                                           // B5

    // ---- Phase A: E = Q * X -> EBUF (kpart dead) ----
#pragma unroll
    for (int rt = 0; rt < 8; ++rt) {
        int row = rt * 16 + n16;
        bf16x8 a0 = *(const bf16x8*)(TBLb + ((row * 128      + q * 16) ^ xr));
        bf16x8 a1 = *(const bf16x8*)(TBLb + ((row * 128 + 64 + q * 16) ^ xr));
#pragma unroll
        for (int ic = 0; ic < 2; ++ic) {
            f32x4 acc = {0.f, 0.f, 0.f, 0.f};
            acc = __builtin_amdgcn_mfma_f32_16x16x32_bf16(a0, xbv[ic][0], acc, 0, 0, 0);
            acc = __builtin_amdgcn_mfma_f32_16x16x32_bf16(a1, xbv[ic][1], acc, 0, 0, 0);
            int c = (2 * w + ic) * 16 + n16;
            uint2 st = make_uint2(packbf2(acc[0], acc[1]), packbf2(acc[2], acc[3]));
            *(uint2*)&EBUF[c * EROW + rt * 16 + q * 4] = st;
        }
    }
    __syncthreads();                                           // B6

    // ---- Phase B: segmented exclusive chunk scan ----
    float mr = m64r, mi = m64i;
    float m32r = mr, m32i = mi;              // r^2048 via 5 squarings
#pragma unroll
    for (int k = 0; k < 5; ++k) {
        float tr = m32r * m32r - m32i * m32i, ti = 2.f * m32r * m32i;
        m32r = tr; m32i = ti;
    }
    {
        float sr = 0.f, si = 0.f;            // pass 1: zero-init segment end
#pragma unroll
        for (int j = 0; j < 32; ++j) {
            uint e = *(const uint*)&EBUF[(g * 32 + j) * EROW + 2 * n];
            float er2 = bf2f((ushort)(e & 0xffffu)), ei2 = bf2f((ushort)(e >> 16));
            float nr = er2 + mr * sr - mi * si;
            float ni = ei2 + mr * si + mi * sr;
            sr = nr; si = ni;
        }
        segr[g * 64 + n] = sr; segi[g * 64 + n] = si;
    }
    // ---- P build in the barrier window (overwrites Q region; Q dead) ----
    {
#pragma unroll
        for (int i = 0; i < 16; ++i) {
            int j = g * 16 + i;
            float pr, pi; rp((float)(j + 1), pr, pi);
            float ur = wr * pr - wi * pi;
            float ui = wr * pi + wi * pr;
            *(uint*)(TBLb + ((j * 256 + n * 4) ^ ((uint)(j & 7) << 4))) = packbf2(ur, -ui);
        }
    }
    __syncthreads();                                           // B7
    {
        float pr2 = 0.f, pi2 = 0.f;          // exclusive prefix over segments
        for (int gp = 0; gp < g; ++gp) {
            float Er = segr[gp * 64 + n], Ei = segi[gp * 64 + n];
            float nr = Er + m32r * pr2 - m32i * pi2;
            float ni = Ei + m32r * pi2 + m32i * pr2;
            pr2 = nr; pi2 = ni;
        }
        float sr = pr2, si = pi2;            // pass 2: replay, write SV in place
#pragma unroll
        for (int j = 0; j < 32; ++j) {
            uint* ep = (uint*)&EBUF[(g * 32 + j) * EROW + 2 * n];
            uint e = *ep;
            float er2 = bf2f((ushort)(e & 0xffffu)), ei2 = bf2f((ushort)(e >> 16));
            *ep = packbf2(sr, si);
            float nr = er2 + mr * sr - mi * si;
            float ni = ei2 + mr * si + mi * sr;
            sr = nr; si = ni;
        }
    }
    __syncthreads();                                           // B8

    // ---- Phase C: OUT = accT + P*SV ----
    float* op = out + (size_t)seq * L_;
#pragma unroll
    for (int rt = 0; rt < 4; ++rt) {
        int row = rt * 16 + n16;
        bf16x8 p0 = *(const bf16x8*)(TBLb + ((row * 256       + q * 16) ^ xr));
        bf16x8 p1 = *(const bf16x8*)(TBLb + ((row * 256 +  64 + q * 16) ^ xr));
        bf16x8 p2 = *(const bf16x8*)(TBLb + ((row * 256 + 128 + q * 16) ^ xr));
        bf16x8 p3 = *(const bf16x8*)(TBLb + ((row * 256 + 192 + q * 16) ^ xr));
#pragma unroll
        for (int ic = 0; ic < 2; ++ic) {
            int c = (2 * w + ic) * 16 + n16;
            f32x4 accP = {0.f, 0.f, 0.f, 0.f};
            accP = __builtin_amdgcn_mfma_f32_16x16x32_bf16(p0,
                       *(const bf16x8*)&EBUF[c * EROW +       q * 8], accP, 0, 0, 0);
            accP = __builtin_amdgcn_mfma_f32_16x16x32_bf16(p1,
                       *(const bf16x8*)&EBUF[c * EROW +  32 + q * 8], accP, 0, 0, 0);
            accP = __builtin_amdgcn_mfma_f32_16x16x32_bf16(p2,
                       *(const bf16x8*)&EBUF[c * EROW +  64 + q * 8], accP, 0, 0, 0);
            accP = __builtin_amdgcn_mfma_f32_16x16x32_bf16(p3,
                       *(const bf16x8*)&EBUF[c * EROW +  96 + q * 8], accP, 0, 0, 0);
            f32x4 o;
            o[0] = accT[rt][ic][0] + accP[0];
            o[1] = accT[rt][ic][1] + accP[1];
            o[2] = accT[rt][ic][2] + accP[2];
            o[3] = accT[rt][ic][3] + accP[3];
            __builtin_nontemporal_store(o, (f32x4*)(op + c * MCH + rt * 16 + q * 4));
        }
    }
}

extern "C" void kernel_launch(void* const* d_in, const int* in_sizes, int n_in,
                              void* d_out, int out_size, void* d_ws, size_t ws_size,
                              hipStream_t stream)
{
    const float* x  = (const float*)d_in[0];
    const float* Ar = (const float*)d_in[1];
    const float* Ai = (const float*)d_in[2];
    const float* C  = (const float*)d_in[3];
    const float* D  = (const float*)d_in[4];
    const float* ld = (const float*)d_in[5];
    float* out = (float*)d_out;
    (void)d_ws; (void)ws_size;               // workspace unused: tables live in LDS

    hipLaunchKernelGGL(s4d_fused, dim3(B_ * H_), dim3(256), 0, stream,
                       x, Ar, Ai, C, D, ld, out);
}

// Round 5
// 108.971 us; speedup vs baseline: 1.0588x; 1.0361x over previous
//
#include <hip/hip_runtime.h>
#include <hip/hip_bf16.h>
#include <math.h>

#define B_ 8
#define H_ 128
#define N_ 64
#define L_ 8192
#define MCH 64                 // chunk length
#define SCH (L_ / MCH)         // 128 chunks per sequence
#define EROW 136               // EBUF row stride (bf16 elems): 272 B, 16B-aligned

// ---- LDS layout (byte offsets) ----
// [0, 34816)       EBUF 128x136 bf16
// [34816, 51200)   TBL 16 KB: Q -> P (sequential lifetimes)
// [51200, 53248)   seg: segr[4][64], segi[4][64] f32
// [53248, 53504)   kv[64] f32
#define LDS_TBL   34816
#define LDS_SEG   51200
#define LDS_KV    53248
#define LDS_TOTAL 53504

typedef __attribute__((ext_vector_type(8))) short bf16x8;  // MFMA A/B frag (4 VGPR)
typedef __attribute__((ext_vector_type(4))) float f32x4;   // MFMA C/D frag / NT vec

__device__ __forceinline__ float bf2f(ushort s) { return __uint_as_float(((uint)s) << 16); }
__device__ __forceinline__ uint packbf2(float a, float b) {
    __hip_bfloat162 h = __float22bfloat162_rn(make_float2(a, b));
    union { __hip_bfloat162 h2; uint u; } cv; cv.h2 = h;
    return cv.u;
}
__device__ __forceinline__ bf16x8 pack_bf8(f32x4 a, f32x4 b) {
    union { uint u[4]; bf16x8 v; } r;
    r.u[0] = packbf2(a[0], a[1]); r.u[1] = packbf2(a[2], a[3]);
    r.u[2] = packbf2(b[0], b[1]); r.u[3] = packbf2(b[2], b[3]);
    return r.v;
}

// ============ single fused kernel, 3-barrier schedule ============
// Key invariant: EBUF rows [32g,32g+32) are written (Phase A), scanned
// (pass1/pass2) and consumed (Phase C) by the SAME wave g -> same-wave LDS
// program order replaces barriers on every EBUF edge. Barriers only on the
// three cross-wave edges: Q+kv ready, Q-dead/seg-ready, P-ready.
__global__ __launch_bounds__(256, 3) void s4d_fused(
    const float* __restrict__ x,
    const float* __restrict__ A_re, const float* __restrict__ A_im,
    const float* __restrict__ Cp, const float* __restrict__ Dp,
    const float* __restrict__ log_delta,
    float* __restrict__ out)
{
    __shared__ __align__(16) char lds[LDS_TOTAL];
    ushort* EBUF  = (ushort*)lds;
    char*   TBLb  = lds + LDS_TBL;
    float*  segr  = (float*)(lds + LDS_SEG);      // [4][64]
    float*  segi  = segr + 256;
    float*  kv    = (float*)(lds + LDS_KV);

    const int seq = blockIdx.x;              // b*H + h
    const int h   = seq % H_;
    const int tid = threadIdx.x;
    const int w   = tid >> 6;                // wave 0..3 -> col-tiles 2w, 2w+1
    const int lane = tid & 63;
    const int n16 = lane & 15, q = lane >> 4;
    const int n = lane;                      // mode index (build + scan)
    const int g = w;

    // ---- per-mode parameters ----
    float are = fminf(A_re[h * N_ + n], -1e-4f);
    float aim = A_im[h * N_ + n];
    float step = expf(log_delta[h]);
    float dre = step * are, dim = step * aim;
    float er = expf(dre);                    // precise r
    float sd, cd; sincosf(dim, &sd, &cd);
    float rre = er * cd, rim = er * sd;
    float cre = Cp[(h * N_ + n) * 2 + 0];
    float cim = Cp[(h * N_ + n) * 2 + 1];
    float inv  = 1.0f / (are * are + aim * aim);
    float numr = rre - 1.0f, numi = rim;
    float consr = (numr * are + numi * aim) * inv;
    float consi = (numi * are - numr * aim) * inv;
    float wr = cre * consr - cim * consi;
    float wi = cre * consi + cim * consr;
    float dval = Dp[h];
    // precise r^64: 6 squarings (feeds the fp32 chunk scan)
    float m64r = rre, m64i = rim;
#pragma unroll
    for (int k = 0; k < 6; ++k) { float tr = m64r*m64r - m64i*m64i, ti = 2.f*m64r*m64i; m64r = tr; m64i = ti; }

    auto rp = [&](float d, float& pr, float& pi) {
        float ex = __expf(d * dre);
        float ang = d * dim;
        float s = __sinf(ang), c2 = __cosf(ang);
        pr = ex * c2; pi = ex * s;
    };

    // ---- X loads (NT): issue first, latency hides under the builds ----
    const float* xs = x + (size_t)seq * L_;
    bf16x8 xbv[2][2];
#pragma unroll
    for (int ic = 0; ic < 2; ++ic) {
        int c = (2 * w + ic) * 16 + n16;
#pragma unroll
        for (int kc = 0; kc < 2; ++kc) {
            const float* p = xs + c * MCH + kc * 32 + q * 8;
            f32x4 f0 = __builtin_nontemporal_load((const f32x4*)p);
            f32x4 f1 = __builtin_nontemporal_load((const f32x4*)p + 1);
            xbv[ic][kc] = pack_bf8(f0, f1);
        }
    }

    // ---- Q build: rows 2n,2n+1, cols [16g,+16), swizzled ----
    {
        uint qr[8], qi[8];
#pragma unroll
        for (int i = 0; i < 8; ++i) {
            int t0 = g * 16 + 2 * i;
            float ar0, ai0, ar1, ai1;
            rp((float)(63 - t0), ar0, ai0);
            rp((float)(62 - t0), ar1, ai1);
            qr[i] = packbf2(ar0, ar1);
            qi[i] = packbf2(ai0, ai1);
        }
        const int ra = 2 * n, rb = 2 * n + 1;
        const uint xa = (uint)(ra & 7) << 4, xbm = (uint)(rb & 7) << 4;
        *(uint4*)(TBLb + ((ra * 128 + g * 32     ) ^ xa)) = ((uint4*)qr)[0];
        *(uint4*)(TBLb + ((ra * 128 + g * 32 + 16) ^ xa)) = ((uint4*)qr)[1];
        *(uint4*)(TBLb + ((rb * 128 + g * 32     ) ^ xbm)) = ((uint4*)qi)[0];
        *(uint4*)(TBLb + ((rb * 128 + g * 32 + 16) ^ xbm)) = ((uint4*)qi)[1];
    }

    // ---- kv[d] = Re(sum_n w r^d): 64-lane butterfly, no LDS staging ----
    {
        float kvloc[16];
#pragma unroll
        for (int j = 0; j < 16; ++j) {
            float pr, pi; rp((float)(g * 16 + j), pr, pi);
            kvloc[j] = wr * pr - wi * pi;
        }
#pragma unroll
        for (int j = 0; j < 16; ++j) {
#pragma unroll
            for (int s = 1; s < 64; s <<= 1)
                kvloc[j] += __shfl_xor(kvloc[j], s, 64);
        }
#pragma unroll
        for (int j = 0; j < 16; ++j)
            if (n == j) kv[g * 16 + j] = kvloc[j];
    }
    __syncthreads();                                     // B1: Q + kv ready

    // ---- Phase A: E = Q * X -> EBUF rows [32w, 32w+32) (own wave) ----
    const uint xr = (uint)(n16 & 7) << 4;
#pragma unroll
    for (int rt = 0; rt < 8; ++rt) {
        int row = rt * 16 + n16;
        bf16x8 a0 = *(const bf16x8*)(TBLb + ((row * 128      + q * 16) ^ xr));
        bf16x8 a1 = *(const bf16x8*)(TBLb + ((row * 128 + 64 + q * 16) ^ xr));
#pragma unroll
        for (int ic = 0; ic < 2; ++ic) {
            f32x4 acc = {0.f, 0.f, 0.f, 0.f};
            acc = __builtin_amdgcn_mfma_f32_16x16x32_bf16(a0, xbv[ic][0], acc, 0, 0, 0);
            acc = __builtin_amdgcn_mfma_f32_16x16x32_bf16(a1, xbv[ic][1], acc, 0, 0, 0);
            int c = (2 * w + ic) * 16 + n16;
            uint2 st = make_uint2(packbf2(acc[0], acc[1]), packbf2(acc[2], acc[3]));
            *(uint2*)&EBUF[c * EROW + rt * 16 + q * 4] = st;
        }
    }

    // ---- scan multipliers ----
    float mr = m64r, mi = m64i;
    float m32r = mr, m32i = mi;              // r^2048 via 5 squarings
#pragma unroll
    for (int k = 0; k < 5; ++k) {
        float tr = m32r * m32r - m32i * m32i, ti = 2.f * m32r * m32i;
        m32r = tr; m32i = ti;
    }

    // ---- pass 1: same-wave EBUF rows -> NO barrier after Phase A ----
    {
        float sr = 0.f, si = 0.f;
#pragma unroll
        for (int j = 0; j < 32; ++j) {
            uint e = *(const uint*)&EBUF[(g * 32 + j) * EROW + 2 * n];
            float er2 = bf2f((ushort)(e & 0xffffu)), ei2 = bf2f((ushort)(e >> 16));
            float nr = er2 + mr * sr - mi * si;
            float ni = ei2 + mr * si + mi * sr;
            sr = nr; si = ni;
        }
        segr[g * 64 + n] = sr; segi[g * 64 + n] = si;
    }

    // ---- T*X from kv (no T table): overlaps pass1's dependent chain ----
    f32x4 accT[4][2];
#pragma unroll
    for (int rt = 0; rt < 4; ++rt) {
        int row = rt * 16 + n16;
        union { uint u[4]; bf16x8 v; } f0, f1;
#pragma unroll
        for (int kc = 0; kc < 2; ++kc) {
#pragma unroll
            for (int ki = 0; ki < 4; ++ki) {
                int t0 = kc * 32 + q * 8 + 2 * ki;
                int i0 = row - t0, i1 = i0 - 1;
                float v0 = kv[i0 & 63]; v0 = (i0 >= 0) ? v0 : 0.f; if (i0 == 0) v0 += dval;
                float v1 = kv[i1 & 63]; v1 = (i1 >= 0) ? v1 : 0.f; if (i1 == 0) v1 += dval;
                if (kc == 0) f0.u[ki] = packbf2(v0, v1); else f1.u[ki] = packbf2(v0, v1);
            }
        }
#pragma unroll
        for (int ic = 0; ic < 2; ++ic) {
            f32x4 a = {0.f, 0.f, 0.f, 0.f};
            a = __builtin_amdgcn_mfma_f32_16x16x32_bf16(f0.v, xbv[ic][0], a, 0, 0, 0);
            a = __builtin_amdgcn_mfma_f32_16x16x32_bf16(f1.v, xbv[ic][1], a, 0, 0, 0);
            accT[rt][ic] = a;
        }
    }
    __syncthreads();                                     // B2: Q dead, seg ready

    // ---- P build (overwrites Q region) ----
#pragma unroll
    for (int i = 0; i < 16; ++i) {
        int j = g * 16 + i;
        float pr, pi; rp((float)(j + 1), pr, pi);
        float ur = wr * pr - wi * pi;
        float ui = wr * pi + wi * pr;
        *(uint*)(TBLb + ((j * 256 + n * 4) ^ ((uint)(j & 7) << 4))) = packbf2(ur, -ui);
    }

    // ---- exclusive seg prefix + pass 2 (same-wave EBUF) ----
    {
        float pr2 = 0.f, pi2 = 0.f;
        for (int gp = 0; gp < g; ++gp) {
            float Er = segr[gp * 64 + n], Ei = segi[gp * 64 + n];
            float nr = Er + m32r * pr2 - m32i * pi2;
            float ni = Ei + m32r * pi2 + m32i * pr2;
            pr2 = nr; pi2 = ni;
        }
        float sr = pr2, si = pi2;
#pragma unroll
        for (int j = 0; j < 32; ++j) {
            uint* ep = (uint*)&EBUF[(g * 32 + j) * EROW + 2 * n];
            uint e = *ep;
            float er2 = bf2f((ushort)(e & 0xffffu)), ei2 = bf2f((ushort)(e >> 16));
            *ep = packbf2(sr, si);
            float nr = er2 + mr * sr - mi * si;
            float ni = ei2 + mr * si + mi * sr;
            sr = nr; si = ni;
        }
    }
    __syncthreads();                                     // B3: P ready

    // ---- Phase C: OUT = accT + P*SV (EBUF rows are own-wave) ----
    float* op = out + (size_t)seq * L_;
#pragma unroll
    for (int rt = 0; rt < 4; ++rt) {
        int row = rt * 16 + n16;
        bf16x8 p0 = *(const bf16x8*)(TBLb + ((row * 256       + q * 16) ^ xr));
        bf16x8 p1 = *(const bf16x8*)(TBLb + ((row * 256 +  64 + q * 16) ^ xr));
        bf16x8 p2 = *(const bf16x8*)(TBLb + ((row * 256 + 128 + q * 16) ^ xr));
        bf16x8 p3 = *(const bf16x8*)(TBLb + ((row * 256 + 192 + q * 16) ^ xr));
#pragma unroll
        for (int ic = 0; ic < 2; ++ic) {
            int c = (2 * w + ic) * 16 + n16;
            f32x4 accP = {0.f, 0.f, 0.f, 0.f};
            accP = __builtin_amdgcn_mfma_f32_16x16x32_bf16(p0,
                       *(const bf16x8*)&EBUF[c * EROW +       q * 8], accP, 0, 0, 0);
            accP = __builtin_amdgcn_mfma_f32_16x16x32_bf16(p1,
                       *(const bf16x8*)&EBUF[c * EROW +  32 + q * 8], accP, 0, 0, 0);
            accP = __builtin_amdgcn_mfma_f32_16x16x32_bf16(p2,
                       *(const bf16x8*)&EBUF[c * EROW +  64 + q * 8], accP, 0, 0, 0);
            accP = __builtin_amdgcn_mfma_f32_16x16x32_bf16(p3,
                       *(const bf16x8*)&EBUF[c * EROW +  96 + q * 8], accP, 0, 0, 0);
            f32x4 o;
            o[0] = accT[rt][ic][0] + accP[0];
            o[1] = accT[rt][ic][1] + accP[1];
            o[2] = accT[rt][ic][2] + accP[2];
            o[3] = accT[rt][ic][3] + accP[3];
            __builtin_nontemporal_store(o, (f32x4*)(op + c * MCH + rt * 16 + q * 4));
        }
    }
}

extern "C" void kernel_launch(void* const* d_in, const int* in_sizes, int n_in,
                              void* d_out, int out_size, void* d_ws, size_t ws_size,
                              hipStream_t stream)
{
    const float* x  = (const float*)d_in[0];
    const float* Ar = (const float*)d_in[1];
    const float* Ai = (const float*)d_in[2];
    const float* C  = (const float*)d_in[3];
    const float* D  = (const float*)d_in[4];
    const float* ld = (const float*)d_in[5];
    float* out = (float*)d_out;
    (void)d_ws; (void)ws_size;               // workspace unused: tables live in LDS

    hipLaunchKernelGGL(s4d_fused, dim3(B_ * H_), dim3(256), 0, stream,
                       x, Ar, Ai, C, D, ld, out);
}

// Round 6
// 103.781 us; speedup vs baseline: 1.1117x; 1.0500x over previous
//
#include <hip/hip_runtime.h>
#include <hip/hip_bf16.h>
#include <math.h>

#define B_ 8
#define H_ 128
#define N_ 64
#define L_ 8192
#define MCH 64                 // chunk length
#define SCH (L_ / MCH)         // 128 chunks per sequence
#define EROW 136               // EBUF row stride (bf16 elems): 272 B, 16B-aligned
#define NSEQ 2                 // sequences per block (same head, b and b+1)

// ---- LDS layout (byte offsets), persistent tables ----
// [0, 34816)       EBUF 128x136 bf16 (per-seq scratch, same-wave rows)
// [34816, 51200)   Q  128x64 bf16 swizzled (persistent)
// [51200, 67584)   P  64x128 bf16 swizzled (persistent)
// [67584, 71680)   seg[2][2][4][64] f32 (double-buffered per seq)
// [71680, 71936)   kv[64] f32
// total 71936 B -> 2 blocks/CU (160 KiB LDS)
#define LDS_Q     34816
#define LDS_P     51200
#define LDS_SEG   67584
#define LDS_KV    71680
#define LDS_TOTAL 71936

typedef __attribute__((ext_vector_type(8))) short bf16x8;  // MFMA A/B frag
typedef __attribute__((ext_vector_type(4))) float f32x4;   // MFMA C/D frag / NT vec

__device__ __forceinline__ float bf2f(ushort s) { return __uint_as_float(((uint)s) << 16); }
__device__ __forceinline__ uint packbf2(float a, float b) {
    __hip_bfloat162 h = __float22bfloat162_rn(make_float2(a, b));
    union { __hip_bfloat162 h2; uint u; } cv; cv.h2 = h;
    return cv.u;
}
__device__ __forceinline__ bf16x8 pack_bf8(f32x4 a, f32x4 b) {
    union { uint u[4]; bf16x8 v; } r;
    r.u[0] = packbf2(a[0], a[1]); r.u[1] = packbf2(a[2], a[3]);
    r.u[2] = packbf2(b[0], b[1]); r.u[3] = packbf2(b[2], b[3]);
    return r.v;
}

// ============ fused kernel, 2 sequences per block ============
// Tables built ONCE per block (amortized over 2 seqs); Q and P persist in
// separate LDS regions. EBUF rows [32g,32g+32) are written/scanned/consumed
// by the SAME wave g in both seqs -> no barriers on EBUF edges. Barriers:
// B1 (tables ready) + one seg-ready barrier per seq = 3 total.
__global__ __launch_bounds__(256, 2) void s4d_fused(
    const float* __restrict__ x,
    const float* __restrict__ A_re, const float* __restrict__ A_im,
    const float* __restrict__ Cp, const float* __restrict__ Dp,
    const float* __restrict__ log_delta,
    float* __restrict__ out)
{
    __shared__ __align__(16) char lds[LDS_TOTAL];
    ushort* EBUF = (ushort*)lds;
    char*   QTBL = lds + LDS_Q;
    char*   PTBL = lds + LDS_P;
    float*  seg  = (float*)(lds + LDS_SEG);   // [sb][r/i][4][64]
    float*  kv   = (float*)(lds + LDS_KV);

    const int h   = blockIdx.x % H_;
    const int bp  = blockIdx.x / H_;          // 0..3 -> b = 2bp, 2bp+1
    const int tid = threadIdx.x;
    const int w   = tid >> 6;
    const int lane = tid & 63;
    const int n16 = lane & 15, q = lane >> 4;
    const int n = lane, g = w;

    // ---- per-mode parameters (once per block) ----
    float are = fminf(A_re[h * N_ + n], -1e-4f);
    float aim = A_im[h * N_ + n];
    float step = expf(log_delta[h]);
    float dre = step * are, dim = step * aim;
    float er = expf(dre);
    float sd, cd; sincosf(dim, &sd, &cd);
    float rre = er * cd, rim = er * sd;
    float cre = Cp[(h * N_ + n) * 2 + 0];
    float cim = Cp[(h * N_ + n) * 2 + 1];
    float inv  = 1.0f / (are * are + aim * aim);
    float numr = rre - 1.0f, numi = rim;
    float consr = (numr * are + numi * aim) * inv;
    float consi = (numi * are - numr * aim) * inv;
    float wr = cre * consr - cim * consi;
    float wi = cre * consi + cim * consr;
    float dval = Dp[h];
    // precise r^64 (6 squarings) and r^2048 (5 more) for the scan
    float m64r = rre, m64i = rim;
#pragma unroll
    for (int k = 0; k < 6; ++k) { float tr = m64r*m64r - m64i*m64i, ti = 2.f*m64r*m64i; m64r = tr; m64i = ti; }
    const float mr = m64r, mi = m64i;
    float m32r = mr, m32i = mi;
#pragma unroll
    for (int k = 0; k < 5; ++k) { float tr = m32r*m32r - m32i*m32i, ti = 2.f*m32r*m32i; m32r = tr; m32i = ti; }

    auto rp = [&](float d, float& pr, float& pi) {
        float ex = __expf(d * dre);
        float ang = d * dim;
        float s = __sinf(ang), c2 = __cosf(ang);
        pr = ex * c2; pi = ex * s;
    };

    // ---- seq pointers ----
    const float* xs0 = x   + ((size_t)(2 * bp) * H_ + h) * L_;
    const float* xs1 = xs0 + (size_t)H_ * L_;
    float* op0 = out + ((size_t)(2 * bp) * H_ + h) * L_;
    float* op1 = op0 + (size_t)H_ * L_;

    // ---- seq0 x load+pack; seq1 raw loads issued now (latency hides
    //      under the whole build + seq0 processing) ----
    bf16x8 xb0[2][2];
    f32x4 raw1[2][2][2];
#pragma unroll
    for (int ic = 0; ic < 2; ++ic) {
        int c = (2 * w + ic) * 16 + n16;
#pragma unroll
        for (int kc = 0; kc < 2; ++kc) {
            const float* p0 = xs0 + c * MCH + kc * 32 + q * 8;
            f32x4 f0 = __builtin_nontemporal_load((const f32x4*)p0);
            f32x4 f1 = __builtin_nontemporal_load((const f32x4*)p0 + 1);
            xb0[ic][kc] = pack_bf8(f0, f1);
            const float* p1 = xs1 + c * MCH + kc * 32 + q * 8;
            raw1[ic][kc][0] = __builtin_nontemporal_load((const f32x4*)p1);
            raw1[ic][kc][1] = __builtin_nontemporal_load((const f32x4*)p1 + 1);
        }
    }

    // ---- Q build: rows 2n,2n+1, cols [16g,+16), swizzled ----
    {
        uint qr[8], qi[8];
#pragma unroll
        for (int i = 0; i < 8; ++i) {
            int t0 = g * 16 + 2 * i;
            float ar0, ai0, ar1, ai1;
            rp((float)(63 - t0), ar0, ai0);
            rp((float)(62 - t0), ar1, ai1);
            qr[i] = packbf2(ar0, ar1);
            qi[i] = packbf2(ai0, ai1);
        }
        const int ra = 2 * n, rb = 2 * n + 1;
        const uint xa = (uint)(ra & 7) << 4, xbm = (uint)(rb & 7) << 4;
        *(uint4*)(QTBL + ((ra * 128 + g * 32     ) ^ xa))  = ((uint4*)qr)[0];
        *(uint4*)(QTBL + ((ra * 128 + g * 32 + 16) ^ xa))  = ((uint4*)qr)[1];
        *(uint4*)(QTBL + ((rb * 128 + g * 32     ) ^ xbm)) = ((uint4*)qi)[0];
        *(uint4*)(QTBL + ((rb * 128 + g * 32 + 16) ^ xbm)) = ((uint4*)qi)[1];
    }

    // ---- kv[d] = Re(sum_n w r^d): 64-lane butterfly ----
    {
        float kvloc[16];
#pragma unroll
        for (int j = 0; j < 16; ++j) {
            float pr, pi; rp((float)(g * 16 + j), pr, pi);
            kvloc[j] = wr * pr - wi * pi;
        }
#pragma unroll
        for (int j = 0; j < 16; ++j) {
#pragma unroll
            for (int s = 1; s < 64; s <<= 1)
                kvloc[j] += __shfl_xor(kvloc[j], s, 64);
        }
#pragma unroll
        for (int j = 0; j < 16; ++j)
            if (n == j) kv[g * 16 + j] = kvloc[j];
    }

    // ---- P build: rows [16g,16g+16), swizzled (own region, persistent) ----
#pragma unroll
    for (int i = 0; i < 16; ++i) {
        int j = g * 16 + i;
        float pr, pi; rp((float)(j + 1), pr, pi);
        float ur = wr * pr - wi * pi;
        float ui = wr * pi + wi * pr;
        *(uint*)(PTBL + ((j * 256 + n * 4) ^ ((uint)(j & 7) << 4))) = packbf2(ur, -ui);
    }
    __syncthreads();                                     // B1: Q, P, kv ready

    // ---- T A-frags from kv (once per block; seq-independent) ----
    bf16x8 tf[4][2];
#pragma unroll
    for (int rt = 0; rt < 4; ++rt) {
        int row = rt * 16 + n16;
        union { uint u[4]; bf16x8 v; } f0, f1;
#pragma unroll
        for (int kc = 0; kc < 2; ++kc) {
#pragma unroll
            for (int ki = 0; ki < 4; ++ki) {
                int t0 = kc * 32 + q * 8 + 2 * ki;
                int i0 = row - t0, i1 = i0 - 1;
                float v0 = kv[i0 & 63]; v0 = (i0 >= 0) ? v0 : 0.f; if (i0 == 0) v0 += dval;
                float v1 = kv[i1 & 63]; v1 = (i1 >= 0) ? v1 : 0.f; if (i1 == 0) v1 += dval;
                if (kc == 0) f0.u[ki] = packbf2(v0, v1); else f1.u[ki] = packbf2(v0, v1);
            }
        }
        tf[rt][0] = f0.v; tf[rt][1] = f1.v;
    }

    const uint xr = (uint)(n16 & 7) << 4;

    // ================= per-sequence processing =================
    auto do_seq = [&](const bf16x8 (&xb)[2][2], int sb, float* op) {
        // ---- Phase A: E = Q * X -> EBUF rows [32w,32w+32) (own wave) ----
#pragma unroll
        for (int rt = 0; rt < 8; ++rt) {
            int row = rt * 16 + n16;
            bf16x8 a0 = *(const bf16x8*)(QTBL + ((row * 128      + q * 16) ^ xr));
            bf16x8 a1 = *(const bf16x8*)(QTBL + ((row * 128 + 64 + q * 16) ^ xr));
#pragma unroll
            for (int ic = 0; ic < 2; ++ic) {
                f32x4 acc = {0.f, 0.f, 0.f, 0.f};
                acc = __builtin_amdgcn_mfma_f32_16x16x32_bf16(a0, xb[ic][0], acc, 0, 0, 0);
                acc = __builtin_amdgcn_mfma_f32_16x16x32_bf16(a1, xb[ic][1], acc, 0, 0, 0);
                int c = (2 * w + ic) * 16 + n16;
                uint2 st = make_uint2(packbf2(acc[0], acc[1]), packbf2(acc[2], acc[3]));
                *(uint2*)&EBUF[c * EROW + rt * 16 + q * 4] = st;
            }
        }

        // ---- pass 1 (same-wave EBUF; no barrier) ----
        float* sr_ = seg + sb * 512;
        float* si_ = sr_ + 256;
        {
            float sr = 0.f, si = 0.f;
#pragma unroll
            for (int j = 0; j < 32; ++j) {
                uint e = *(const uint*)&EBUF[(g * 32 + j) * EROW + 2 * n];
                float er2 = bf2f((ushort)(e & 0xffffu)), ei2 = bf2f((ushort)(e >> 16));
                float nr = er2 + mr * sr - mi * si;
                float ni = ei2 + mr * si + mi * sr;
                sr = nr; si = ni;
            }
            sr_[g * 64 + n] = sr; si_[g * 64 + n] = si;
        }

        // ---- T*X (overlaps pass1's dependent chain) ----
        f32x4 accT[4][2];
#pragma unroll
        for (int rt = 0; rt < 4; ++rt) {
#pragma unroll
            for (int ic = 0; ic < 2; ++ic) {
                f32x4 a = {0.f, 0.f, 0.f, 0.f};
                a = __builtin_amdgcn_mfma_f32_16x16x32_bf16(tf[rt][0], xb[ic][0], a, 0, 0, 0);
                a = __builtin_amdgcn_mfma_f32_16x16x32_bf16(tf[rt][1], xb[ic][1], a, 0, 0, 0);
                accT[rt][ic] = a;
            }
        }
        __syncthreads();                                 // seg[sb] ready

        // ---- exclusive seg prefix + pass 2 (same-wave EBUF) ----
        {
            float pr2 = 0.f, pi2 = 0.f;
            for (int gp = 0; gp < g; ++gp) {
                float Er = sr_[gp * 64 + n], Ei = si_[gp * 64 + n];
                float nr = Er + m32r * pr2 - m32i * pi2;
                float ni = Ei + m32r * pi2 + m32i * pr2;
                pr2 = nr; pi2 = ni;
            }
            float sr = pr2, si = pi2;
#pragma unroll
            for (int j = 0; j < 32; ++j) {
                uint* ep = (uint*)&EBUF[(g * 32 + j) * EROW + 2 * n];
                uint e = *ep;
                float er2 = bf2f((ushort)(e & 0xffffu)), ei2 = bf2f((ushort)(e >> 16));
                *ep = packbf2(sr, si);
                float nr = er2 + mr * sr - mi * si;
                float ni = ei2 + mr * si + mi * sr;
                sr = nr; si = ni;
            }
        }

        // ---- Phase C: OUT = accT + P*SV (own-wave EBUF rows) ----
#pragma unroll
        for (int rt = 0; rt < 4; ++rt) {
            int row = rt * 16 + n16;
            bf16x8 p0 = *(const bf16x8*)(PTBL + ((row * 256       + q * 16) ^ xr));
            bf16x8 p1 = *(const bf16x8*)(PTBL + ((row * 256 +  64 + q * 16) ^ xr));
            bf16x8 p2 = *(const bf16x8*)(PTBL + ((row * 256 + 128 + q * 16) ^ xr));
            bf16x8 p3 = *(const bf16x8*)(PTBL + ((row * 256 + 192 + q * 16) ^ xr));
#pragma unroll
            for (int ic = 0; ic < 2; ++ic) {
                int c = (2 * w + ic) * 16 + n16;
                f32x4 accP = {0.f, 0.f, 0.f, 0.f};
                accP = __builtin_amdgcn_mfma_f32_16x16x32_bf16(p0,
                           *(const bf16x8*)&EBUF[c * EROW +       q * 8], accP, 0, 0, 0);
                accP = __builtin_amdgcn_mfma_f32_16x16x32_bf16(p1,
                           *(const bf16x8*)&EBUF[c * EROW +  32 + q * 8], accP, 0, 0, 0);
                accP = __builtin_amdgcn_mfma_f32_16x16x32_bf16(p2,
                           *(const bf16x8*)&EBUF[c * EROW +  64 + q * 8], accP, 0, 0, 0);
                accP = __builtin_amdgcn_mfma_f32_16x16x32_bf16(p3,
                           *(const bf16x8*)&EBUF[c * EROW +  96 + q * 8], accP, 0, 0, 0);
                f32x4 o;
                o[0] = accT[rt][ic][0] + accP[0];
                o[1] = accT[rt][ic][1] + accP[1];
                o[2] = accT[rt][ic][2] + accP[2];
                o[3] = accT[rt][ic][3] + accP[3];
                __builtin_nontemporal_store(o, (f32x4*)(op + c * MCH + rt * 16 + q * 4));
            }
        }
    };

    do_seq(xb0, 0, op0);

    // pack seq1 (loads issued at block start; compiler waits here)
    bf16x8 xb1[2][2];
#pragma unroll
    for (int ic = 0; ic < 2; ++ic)
#pragma unroll
        for (int kc = 0; kc < 2; ++kc)
            xb1[ic][kc] = pack_bf8(raw1[ic][kc][0], raw1[ic][kc][1]);

    do_seq(xb1, 1, op1);
}

extern "C" void kernel_launch(void* const* d_in, const int* in_sizes, int n_in,
                              void* d_out, int out_size, void* d_ws, size_t ws_size,
                              hipStream_t stream)
{
    const float* x  = (const float*)d_in[0];
    const float* Ar = (const float*)d_in[1];
    const float* Ai = (const float*)d_in[2];
    const float* C  = (const float*)d_in[3];
    const float* D  = (const float*)d_in[4];
    const float* ld = (const float*)d_in[5];
    float* out = (float*)d_out;
    (void)d_ws; (void)ws_size;               // workspace unused: tables live in LDS

    hipLaunchKernelGGL(s4d_fused, dim3(B_ * H_ / NSEQ), dim3(256), 0, stream,
                       x, Ar, Ai, C, D, ld, out);
}

// Round 7
// 103.246 us; speedup vs baseline: 1.1175x; 1.0052x over previous
//
#include <hip/hip_runtime.h>
#include <hip/hip_bf16.h>
#include <math.h>

#define B_ 8
#define H_ 128
#define N_ 64
#define L_ 8192
#define MCH 64                 // chunk length
#define SCH (L_ / MCH)         // 128 chunks per sequence
#define EROW 136               // EBUF row stride (bf16 elems): 272 B, 16B-aligned
#define NSEQ 2                 // sequences per block (same head, b and b+1)

// ---- LDS layout (byte offsets), persistent tables ----
// [0, 34816)       EBUF 128x136 bf16 (per-seq scratch, same-wave rows)
// [34816, 51200)   Q  128x64 bf16 swizzled (persistent)
// [51200, 67584)   P  64x128 bf16 swizzled (persistent)
// [67584, 75776)   seg[2][2][8][64] f32 (double-buffered per seq, 8 segments)
// [75776, 76032)   kv[64] f32
// total 76032 B -> 2 blocks/CU (160 KiB LDS)
#define LDS_Q     34816
#define LDS_P     51200
#define LDS_SEG   67584
#define LDS_KV    75776
#define LDS_TOTAL 76032

typedef __attribute__((ext_vector_type(8))) short bf16x8;  // MFMA A/B frag
typedef __attribute__((ext_vector_type(4))) float f32x4;   // MFMA C/D frag / NT vec

__device__ __forceinline__ float bf2f(ushort s) { return __uint_as_float(((uint)s) << 16); }
__device__ __forceinline__ uint packbf2(float a, float b) {
    __hip_bfloat162 h = __float22bfloat162_rn(make_float2(a, b));
    union { __hip_bfloat162 h2; uint u; } cv; cv.h2 = h;
    return cv.u;
}
__device__ __forceinline__ bf16x8 pack_bf8(f32x4 a, f32x4 b) {
    union { uint u[4]; bf16x8 v; } r;
    r.u[0] = packbf2(a[0], a[1]); r.u[1] = packbf2(a[2], a[3]);
    r.u[2] = packbf2(b[0], b[1]); r.u[3] = packbf2(b[2], b[3]);
    return r.v;
}

// ============ fused kernel, 2 sequences per block ============
// Tables built once per block; Q and P persist in LDS. EBUF rows [32g,32g+32)
// are written/scanned/consumed by the SAME wave g in both seqs -> no barriers
// on EBUF edges. Scan: 8 segments x 16 chunks; each wave runs 2 interleaved
// 16-step chains (2-way ILP on the dependent complex-MAC chain).
__global__ __launch_bounds__(256, 2) void s4d_fused(
    const float* __restrict__ x,
    const float* __restrict__ A_re, const float* __restrict__ A_im,
    const float* __restrict__ Cp, const float* __restrict__ Dp,
    const float* __restrict__ log_delta,
    float* __restrict__ out)
{
    __shared__ __align__(16) char lds[LDS_TOTAL];
    ushort* EBUF = (ushort*)lds;
    char*   QTBL = lds + LDS_Q;
    char*   PTBL = lds + LDS_P;
    float*  seg  = (float*)(lds + LDS_SEG);   // [sb][r/i][8][64]
    float*  kv   = (float*)(lds + LDS_KV);

    const int h   = blockIdx.x % H_;
    const int bp  = blockIdx.x / H_;          // 0..3 -> b = 2bp, 2bp+1
    const int tid = threadIdx.x;
    const int w   = tid >> 6;
    const int lane = tid & 63;
    const int n16 = lane & 15, q = lane >> 4;
    const int n = lane, g = w;

    // ---- per-mode parameters (once per block) ----
    float are = fminf(A_re[h * N_ + n], -1e-4f);
    float aim = A_im[h * N_ + n];
    float step = expf(log_delta[h]);
    float dre = step * are, dim = step * aim;
    float er = expf(dre);
    float sd, cd; sincosf(dim, &sd, &cd);
    float rre = er * cd, rim = er * sd;
    float cre = Cp[(h * N_ + n) * 2 + 0];
    float cim = Cp[(h * N_ + n) * 2 + 1];
    float inv  = 1.0f / (are * are + aim * aim);
    float numr = rre - 1.0f, numi = rim;
    float consr = (numr * are + numi * aim) * inv;
    float consi = (numi * are - numr * aim) * inv;
    float wr = cre * consr - cim * consi;
    float wi = cre * consi + cim * consr;
    float dval = Dp[h];
    // precise r^64 (6 squarings); r^1024 = m16 (4 more) for segment prefix
    float m64r = rre, m64i = rim;
#pragma unroll
    for (int k = 0; k < 6; ++k) { float tr = m64r*m64r - m64i*m64i, ti = 2.f*m64r*m64i; m64r = tr; m64i = ti; }
    const float mr = m64r, mi = m64i;

    auto rp = [&](float d, float& pr, float& pi) {
        float ex = __expf(d * dre);
        float ang = d * dim;
        float s = __sinf(ang), c2 = __cosf(ang);
        pr = ex * c2; pi = ex * s;
    };

    // ---- seq pointers ----
    const float* xs0 = x   + ((size_t)(2 * bp) * H_ + h) * L_;
    const float* xs1 = xs0 + (size_t)H_ * L_;
    float* op0 = out + ((size_t)(2 * bp) * H_ + h) * L_;
    float* op1 = op0 + (size_t)H_ * L_;

    // ---- seq0 x load+pack; seq1 raw loads issued now ----
    bf16x8 xb0[2][2];
    f32x4 raw1[2][2][2];
#pragma unroll
    for (int ic = 0; ic < 2; ++ic) {
        int c = (2 * w + ic) * 16 + n16;
#pragma unroll
        for (int kc = 0; kc < 2; ++kc) {
            const float* p0 = xs0 + c * MCH + kc * 32 + q * 8;
            f32x4 f0 = __builtin_nontemporal_load((const f32x4*)p0);
            f32x4 f1 = __builtin_nontemporal_load((const f32x4*)p0 + 1);
            xb0[ic][kc] = pack_bf8(f0, f1);
            const float* p1 = xs1 + c * MCH + kc * 32 + q * 8;
            raw1[ic][kc][0] = __builtin_nontemporal_load((const f32x4*)p1);
            raw1[ic][kc][1] = __builtin_nontemporal_load((const f32x4*)p1 + 1);
        }
    }

    // ---- Q build: rows 2n,2n+1, cols [16g,+16), swizzled ----
    {
        uint qr[8], qi[8];
#pragma unroll
        for (int i = 0; i < 8; ++i) {
            int t0 = g * 16 + 2 * i;
            float ar0, ai0, ar1, ai1;
            rp((float)(63 - t0), ar0, ai0);
            rp((float)(62 - t0), ar1, ai1);
            qr[i] = packbf2(ar0, ar1);
            qi[i] = packbf2(ai0, ai1);
        }
        const int ra = 2 * n, rb = 2 * n + 1;
        const uint xa = (uint)(ra & 7) << 4, xbm = (uint)(rb & 7) << 4;
        *(uint4*)(QTBL + ((ra * 128 + g * 32     ) ^ xa))  = ((uint4*)qr)[0];
        *(uint4*)(QTBL + ((ra * 128 + g * 32 + 16) ^ xa))  = ((uint4*)qr)[1];
        *(uint4*)(QTBL + ((rb * 128 + g * 32     ) ^ xbm)) = ((uint4*)qi)[0];
        *(uint4*)(QTBL + ((rb * 128 + g * 32 + 16) ^ xbm)) = ((uint4*)qi)[1];
    }

    // ---- kv[d] = Re(sum_n w r^d): 64-lane butterfly ----
    {
        float kvloc[16];
#pragma unroll
        for (int j = 0; j < 16; ++j) {
            float pr, pi; rp((float)(g * 16 + j), pr, pi);
            kvloc[j] = wr * pr - wi * pi;
        }
#pragma unroll
        for (int j = 0; j < 16; ++j) {
#pragma unroll
            for (int s = 1; s < 64; s <<= 1)
                kvloc[j] += __shfl_xor(kvloc[j], s, 64);
        }
#pragma unroll
        for (int j = 0; j < 16; ++j)
            if (n == j) kv[g * 16 + j] = kvloc[j];
    }
    __syncthreads();                                     // B1: Q, kv ready

    // ---- m16 = r^1024 (4 squarings from r^64): segment-prefix multiplier ----
    float m16r = mr, m16i = mi;
#pragma unroll
    for (int k = 0; k < 4; ++k) { float tr = m16r*m16r - m16i*m16i, ti = 2.f*m16r*m16i; m16r = tr; m16i = ti; }

    // ---- T A-frags from kv (once per block; overlaps whatever follows) ----
    bf16x8 tf[4][2];
#pragma unroll
    for (int rt = 0; rt < 4; ++rt) {
        int row = rt * 16 + n16;
        union { uint u[4]; bf16x8 v; } f0, f1;
#pragma unroll
        for (int kc = 0; kc < 2; ++kc) {
#pragma unroll
            for (int ki = 0; ki < 4; ++ki) {
                int t0 = kc * 32 + q * 8 + 2 * ki;
                int i0 = row - t0, i1 = i0 - 1;
                float v0 = kv[i0 & 63]; v0 = (i0 >= 0) ? v0 : 0.f; if (i0 == 0) v0 += dval;
                float v1 = kv[i1 & 63]; v1 = (i1 >= 0) ? v1 : 0.f; if (i1 == 0) v1 += dval;
                if (kc == 0) f0.u[ki] = packbf2(v0, v1); else f1.u[ki] = packbf2(v0, v1);
            }
        }
        tf[rt][0] = f0.v; tf[rt][1] = f1.v;
    }

    const uint xr = (uint)(n16 & 7) << 4;

    // ================= per-sequence processing =================
    auto do_seq = [&](const bf16x8 (&xb)[2][2], int sb, float* op, bool buildP) {
        // ---- Phase A: E = Q * X -> EBUF rows [32w,32w+32) (own wave) ----
#pragma unroll
        for (int rt = 0; rt < 8; ++rt) {
            int row = rt * 16 + n16;
            bf16x8 a0 = *(const bf16x8*)(QTBL + ((row * 128      + q * 16) ^ xr));
            bf16x8 a1 = *(const bf16x8*)(QTBL + ((row * 128 + 64 + q * 16) ^ xr));
#pragma unroll
            for (int ic = 0; ic < 2; ++ic) {
                f32x4 acc = {0.f, 0.f, 0.f, 0.f};
                acc = __builtin_amdgcn_mfma_f32_16x16x32_bf16(a0, xb[ic][0], acc, 0, 0, 0);
                acc = __builtin_amdgcn_mfma_f32_16x16x32_bf16(a1, xb[ic][1], acc, 0, 0, 0);
                int c = (2 * w + ic) * 16 + n16;
                uint2 st = make_uint2(packbf2(acc[0], acc[1]), packbf2(acc[2], acc[3]));
                *(uint2*)&EBUF[c * EROW + rt * 16 + q * 4] = st;
            }
        }

        // ---- pass 1: two interleaved 16-chains (same-wave EBUF) ----
        float* sr_ = seg + sb * 1024;         // [r][8][64]
        float* si_ = sr_ + 512;
        {
            float sAr = 0.f, sAi = 0.f, sBr = 0.f, sBi = 0.f;
#pragma unroll
            for (int j = 0; j < 16; ++j) {
                uint eA = *(const uint*)&EBUF[(g * 32 + j     ) * EROW + 2 * n];
                uint eB = *(const uint*)&EBUF[(g * 32 + 16 + j) * EROW + 2 * n];
                float eAr = bf2f((ushort)(eA & 0xffffu)), eAi = bf2f((ushort)(eA >> 16));
                float eBr = bf2f((ushort)(eB & 0xffffu)), eBi = bf2f((ushort)(eB >> 16));
                float nAr = eAr + mr * sAr - mi * sAi;
                float nAi = eAi + mr * sAi + mi * sAr;
                float nBr = eBr + mr * sBr - mi * sBi;
                float nBi = eBi + mr * sBi + mi * sBr;
                sAr = nAr; sAi = nAi; sBr = nBr; sBi = nBi;
            }
            sr_[(2 * g    ) * 64 + n] = sAr; si_[(2 * g    ) * 64 + n] = sAi;
            sr_[(2 * g + 1) * 64 + n] = sBr; si_[(2 * g + 1) * 64 + n] = sBi;
        }

        // ---- T*X (overlaps pass1's dependent chain) ----
        f32x4 accT[4][2];
#pragma unroll
        for (int rt = 0; rt < 4; ++rt) {
#pragma unroll
            for (int ic = 0; ic < 2; ++ic) {
                f32x4 a = {0.f, 0.f, 0.f, 0.f};
                a = __builtin_amdgcn_mfma_f32_16x16x32_bf16(tf[rt][0], xb[ic][0], a, 0, 0, 0);
                a = __builtin_amdgcn_mfma_f32_16x16x32_bf16(tf[rt][1], xb[ic][1], a, 0, 0, 0);
                accT[rt][ic] = a;
            }
        }

        // ---- P build (seq0 only; ordered before Phase C by the barrier) ----
        if (buildP) {
#pragma unroll
            for (int i = 0; i < 16; ++i) {
                int j = g * 16 + i;
                float pr, pi; rp((float)(j + 1), pr, pi);
                float ur = wr * pr - wi * pi;
                float ui = wr * pi + wi * pr;
                *(uint*)(PTBL + ((j * 256 + n * 4) ^ ((uint)(j & 7) << 4))) = packbf2(ur, -ui);
            }
        }
        __syncthreads();                                 // seg[sb] (+P) ready

        // ---- exclusive seg prefix (<=7 terms) + pass 2 (2 chains) ----
        {
            float pr2 = 0.f, pi2 = 0.f;
            for (int s = 0; s < 2 * g; ++s) {
                float Er = sr_[s * 64 + n], Ei = si_[s * 64 + n];
                float nr = Er + m16r * pr2 - m16i * pi2;
                float ni = Ei + m16r * pi2 + m16i * pr2;
                pr2 = nr; pi2 = ni;
            }
            float sAr = pr2, sAi = pi2;
            float Gr = sr_[(2 * g) * 64 + n], Gi = si_[(2 * g) * 64 + n];
            float sBr = Gr + m16r * pr2 - m16i * pi2;
            float sBi = Gi + m16r * pi2 + m16i * pr2;
#pragma unroll
            for (int j = 0; j < 16; ++j) {
                uint* epA = (uint*)&EBUF[(g * 32 + j     ) * EROW + 2 * n];
                uint* epB = (uint*)&EBUF[(g * 32 + 16 + j) * EROW + 2 * n];
                uint eA = *epA, eB = *epB;
                float eAr = bf2f((ushort)(eA & 0xffffu)), eAi = bf2f((ushort)(eA >> 16));
                float eBr = bf2f((ushort)(eB & 0xffffu)), eBi = bf2f((ushort)(eB >> 16));
                *epA = packbf2(sAr, sAi);
                *epB = packbf2(sBr, sBi);
                float nAr = eAr + mr * sAr - mi * sAi;
                float nAi = eAi + mr * sAi + mi * sAr;
                float nBr = eBr + mr * sBr - mi * sBi;
                float nBi = eBi + mr * sBi + mi * sBr;
                sAr = nAr; sAi = nAi; sBr = nBr; sBi = nBi;
            }
        }

        // ---- Phase C: OUT = accT + P*SV (own-wave EBUF rows) ----
#pragma unroll
        for (int rt = 0; rt < 4; ++rt) {
            int row = rt * 16 + n16;
            bf16x8 p0 = *(const bf16x8*)(PTBL + ((row * 256       + q * 16) ^ xr));
            bf16x8 p1 = *(const bf16x8*)(PTBL + ((row * 256 +  64 + q * 16) ^ xr));
            bf16x8 p2 = *(const bf16x8*)(PTBL + ((row * 256 + 128 + q * 16) ^ xr));
            bf16x8 p3 = *(const bf16x8*)(PTBL + ((row * 256 + 192 + q * 16) ^ xr));
#pragma unroll
            for (int ic = 0; ic < 2; ++ic) {
                int c = (2 * w + ic) * 16 + n16;
                f32x4 accP = {0.f, 0.f, 0.f, 0.f};
                accP = __builtin_amdgcn_mfma_f32_16x16x32_bf16(p0,
                           *(const bf16x8*)&EBUF[c * EROW +       q * 8], accP, 0, 0, 0);
                accP = __builtin_amdgcn_mfma_f32_16x16x32_bf16(p1,
                           *(const bf16x8*)&EBUF[c * EROW +  32 + q * 8], accP, 0, 0, 0);
                accP = __builtin_amdgcn_mfma_f32_16x16x32_bf16(p2,
                           *(const bf16x8*)&EBUF[c * EROW +  64 + q * 8], accP, 0, 0, 0);
                accP = __builtin_amdgcn_mfma_f32_16x16x32_bf16(p3,
                           *(const bf16x8*)&EBUF[c * EROW +  96 + q * 8], accP, 0, 0, 0);
                f32x4 o;
                o[0] = accT[rt][ic][0] + accP[0];
                o[1] = accT[rt][ic][1] + accP[1];
                o[2] = accT[rt][ic][2] + accP[2];
                o[3] = accT[rt][ic][3] + accP[3];
                __builtin_nontemporal_store(o, (f32x4*)(op + c * MCH + rt * 16 + q * 4));
            }
        }
    };

    do_seq(xb0, 0, op0, true);

    // pack seq1 (loads issued at block start; compiler waits here)
    bf16x8 xb1[2][2];
#pragma unroll
    for (int ic = 0; ic < 2; ++ic)
#pragma unroll
        for (int kc = 0; kc < 2; ++kc)
            xb1[ic][kc] = pack_bf8(raw1[ic][kc][0], raw1[ic][kc][1]);

    do_seq(xb1, 1, op1, false);
}

extern "C" void kernel_launch(void* const* d_in, const int* in_sizes, int n_in,
                              void* d_out, int out_size, void* d_ws, size_t ws_size,
                              hipStream_t stream)
{
    const float* x  = (const float*)d_in[0];
    const float* Ar = (const float*)d_in[1];
    const float* Ai = (const float*)d_in[2];
    const float* C  = (const float*)d_in[3];
    const float* D  = (const float*)d_in[4];
    const float* ld = (const float*)d_in[5];
    float* out = (float*)d_out;
    (void)d_ws; (void)ws_size;               // workspace unused: tables live in LDS

    hipLaunchKernelGGL(s4d_fused, dim3(B_ * H_ / NSEQ), dim3(256), 0, stream,
                       x, Ar, Ai, C, D, ld, out);
}

// Round 8
// 101.689 us; speedup vs baseline: 1.1346x; 1.0153x over previous
//
#include <hip/hip_runtime.h>
#include <hip/hip_bf16.h>
#include <math.h>

#define B_ 8
#define H_ 128
#define N_ 64
#define L_ 8192
#define MCH 64                 // chunk length
#define SCH (L_ / MCH)         // 128 chunks per sequence
#define EROW 136               // EBUF row stride (bf16 elems): 272 B, 16B-aligned
#define NSEQ 2                 // sequences per block (same head, b and b+1)

// ---- LDS layout (byte offsets), persistent tables ----
// [0, 34816)       EBUF 128x136 bf16 (per-seq scratch, same-wave rows)
// [34816, 51200)   Q  128x64 bf16 swizzled (persistent)
// [51200, 67584)   P  64x128 bf16 swizzled (persistent)
// [67584, 75776)   seg[2][2][8][64] f32 (double-buffered per seq, 8 segments)
// [75776, 76032)   kv[64] f32
// total 76032 B -> 2 blocks/CU (160 KiB LDS)
#define LDS_Q     34816
#define LDS_P     51200
#define LDS_SEG   67584
#define LDS_KV    75776
#define LDS_TOTAL 76032

typedef __attribute__((ext_vector_type(8))) short bf16x8;  // MFMA A/B frag
typedef __attribute__((ext_vector_type(4))) float f32x4;   // MFMA C/D frag / NT vec

__device__ __forceinline__ float bf2f(ushort s) { return __uint_as_float(((uint)s) << 16); }
__device__ __forceinline__ uint packbf2(float a, float b) {
    __hip_bfloat162 h = __float22bfloat162_rn(make_float2(a, b));
    union { __hip_bfloat162 h2; uint u; } cv; cv.h2 = h;
    return cv.u;
}
__device__ __forceinline__ bf16x8 pack_bf8(f32x4 a, f32x4 b) {
    union { uint u[4]; bf16x8 v; } r;
    r.u[0] = packbf2(a[0], a[1]); r.u[1] = packbf2(a[2], a[3]);
    r.u[2] = packbf2(b[0], b[1]); r.u[3] = packbf2(b[2], b[3]);
    return r.v;
}

// ============ fused kernel, 2 sequences per block ============
// Tables built once per block; Q and P persist in LDS. EBUF rows [32g,32g+32)
// are written/scanned/consumed by the SAME wave g in both seqs -> no barriers
// on EBUF edges. seq1's x-loads are issued AFTER seq0's Phase A so the
// device-wide read stream overlaps seq0's compute and store stream
// (de-phased memory pipeline instead of phase-locked bursts).
__global__ __launch_bounds__(256, 2) void s4d_fused(
    const float* __restrict__ x,
    const float* __restrict__ A_re, const float* __restrict__ A_im,
    const float* __restrict__ Cp, const float* __restrict__ Dp,
    const float* __restrict__ log_delta,
    float* __restrict__ out)
{
    __shared__ __align__(16) char lds[LDS_TOTAL];
    ushort* EBUF = (ushort*)lds;
    char*   QTBL = lds + LDS_Q;
    char*   PTBL = lds + LDS_P;
    float*  seg  = (float*)(lds + LDS_SEG);   // [sb][r/i][8][64]
    float*  kv   = (float*)(lds + LDS_KV);

    const int h   = blockIdx.x % H_;
    const int bp  = blockIdx.x / H_;          // 0..3 -> b = 2bp, 2bp+1
    const int tid = threadIdx.x;
    const int w   = tid >> 6;
    const int lane = tid & 63;
    const int n16 = lane & 15, q = lane >> 4;
    const int n = lane, g = w;

    // ---- per-mode parameters (once per block) ----
    float are = fminf(A_re[h * N_ + n], -1e-4f);
    float aim = A_im[h * N_ + n];
    float step = expf(log_delta[h]);
    float dre = step * are, dim = step * aim;
    float er = expf(dre);
    float sd, cd; sincosf(dim, &sd, &cd);
    float rre = er * cd, rim = er * sd;
    float cre = Cp[(h * N_ + n) * 2 + 0];
    float cim = Cp[(h * N_ + n) * 2 + 1];
    float inv  = 1.0f / (are * are + aim * aim);
    float numr = rre - 1.0f, numi = rim;
    float consr = (numr * are + numi * aim) * inv;
    float consi = (numi * are - numr * aim) * inv;
    float wr = cre * consr - cim * consi;
    float wi = cre * consi + cim * consr;
    float dval = Dp[h];
    // precise r^64 (6 squarings); segment multiplier m16 = r^1024 later
    float m64r = rre, m64i = rim;
#pragma unroll
    for (int k = 0; k < 6; ++k) { float tr = m64r*m64r - m64i*m64i, ti = 2.f*m64r*m64i; m64r = tr; m64i = ti; }
    const float mr = m64r, mi = m64i;

    auto rp = [&](float d, float& pr, float& pi) {
        float ex = __expf(d * dre);
        float ang = d * dim;
        float s = __sinf(ang), c2 = __cosf(ang);
        pr = ex * c2; pi = ex * s;
    };

    // ---- seq pointers ----
    const float* xs0 = x   + ((size_t)(2 * bp) * H_ + h) * L_;
    const float* xs1 = xs0 + (size_t)H_ * L_;
    float* op0 = out + ((size_t)(2 * bp) * H_ + h) * L_;
    float* op1 = op0 + (size_t)H_ * L_;

    // ---- seq0 x load+pack only (seq1 loads issued after seq0 Phase A) ----
    bf16x8 xb0[2][2];
    f32x4 raw1[2][2][2];
#pragma unroll
    for (int ic = 0; ic < 2; ++ic) {
        int c = (2 * w + ic) * 16 + n16;
#pragma unroll
        for (int kc = 0; kc < 2; ++kc) {
            const float* p0 = xs0 + c * MCH + kc * 32 + q * 8;
            f32x4 f0 = __builtin_nontemporal_load((const f32x4*)p0);
            f32x4 f1 = __builtin_nontemporal_load((const f32x4*)p0 + 1);
            xb0[ic][kc] = pack_bf8(f0, f1);
        }
    }

    // ---- Q build: rows 2n,2n+1, cols [16g,+16), swizzled ----
    {
        uint qr[8], qi[8];
#pragma unroll
        for (int i = 0; i < 8; ++i) {
            int t0 = g * 16 + 2 * i;
            float ar0, ai0, ar1, ai1;
            rp((float)(63 - t0), ar0, ai0);
            rp((float)(62 - t0), ar1, ai1);
            qr[i] = packbf2(ar0, ar1);
            qi[i] = packbf2(ai0, ai1);
        }
        const int ra = 2 * n, rb = 2 * n + 1;
        const uint xa = (uint)(ra & 7) << 4, xbm = (uint)(rb & 7) << 4;
        *(uint4*)(QTBL + ((ra * 128 + g * 32     ) ^ xa))  = ((uint4*)qr)[0];
        *(uint4*)(QTBL + ((ra * 128 + g * 32 + 16) ^ xa))  = ((uint4*)qr)[1];
        *(uint4*)(QTBL + ((rb * 128 + g * 32     ) ^ xbm)) = ((uint4*)qi)[0];
        *(uint4*)(QTBL + ((rb * 128 + g * 32 + 16) ^ xbm)) = ((uint4*)qi)[1];
    }

    // ---- kv[d] = Re(sum_n w r^d): 64-lane butterfly ----
    {
        float kvloc[16];
#pragma unroll
        for (int j = 0; j < 16; ++j) {
            float pr, pi; rp((float)(g * 16 + j), pr, pi);
            kvloc[j] = wr * pr - wi * pi;
        }
#pragma unroll
        for (int j = 0; j < 16; ++j) {
#pragma unroll
            for (int s = 1; s < 64; s <<= 1)
                kvloc[j] += __shfl_xor(kvloc[j], s, 64);
        }
#pragma unroll
        for (int j = 0; j < 16; ++j)
            if (n == j) kv[g * 16 + j] = kvloc[j];
    }
    __syncthreads();                                     // B1: Q, kv ready

    // ---- m16 = r^1024 (4 squarings from r^64): segment-prefix multiplier ----
    float m16r = mr, m16i = mi;
#pragma unroll
    for (int k = 0; k < 4; ++k) { float tr = m16r*m16r - m16i*m16i, ti = 2.f*m16r*m16i; m16r = tr; m16i = ti; }

    // ---- T A-frags from kv (once per block) ----
    bf16x8 tf[4][2];
#pragma unroll
    for (int rt = 0; rt < 4; ++rt) {
        int row = rt * 16 + n16;
        union { uint u[4]; bf16x8 v; } f0, f1;
#pragma unroll
        for (int kc = 0; kc < 2; ++kc) {
#pragma unroll
            for (int ki = 0; ki < 4; ++ki) {
                int t0 = kc * 32 + q * 8 + 2 * ki;
                int i0 = row - t0, i1 = i0 - 1;
                float v0 = kv[i0 & 63]; v0 = (i0 >= 0) ? v0 : 0.f; if (i0 == 0) v0 += dval;
                float v1 = kv[i1 & 63]; v1 = (i1 >= 0) ? v1 : 0.f; if (i1 == 0) v1 += dval;
                if (kc == 0) f0.u[ki] = packbf2(v0, v1); else f1.u[ki] = packbf2(v0, v1);
            }
        }
        tf[rt][0] = f0.v; tf[rt][1] = f1.v;
    }

    const uint xr = (uint)(n16 & 7) << 4;

    // ================= per-sequence processing =================
    auto do_seq = [&](const bf16x8 (&xb)[2][2], int sb, float* op,
                      bool buildP, bool issueRaw1) {
        // ---- Phase A: E = Q * X -> EBUF rows [32w,32w+32) (own wave) ----
#pragma unroll
        for (int rt = 0; rt < 8; ++rt) {
            int row = rt * 16 + n16;
            bf16x8 a0 = *(const bf16x8*)(QTBL + ((row * 128      + q * 16) ^ xr));
            bf16x8 a1 = *(const bf16x8*)(QTBL + ((row * 128 + 64 + q * 16) ^ xr));
#pragma unroll
            for (int ic = 0; ic < 2; ++ic) {
                f32x4 acc = {0.f, 0.f, 0.f, 0.f};
                acc = __builtin_amdgcn_mfma_f32_16x16x32_bf16(a0, xb[ic][0], acc, 0, 0, 0);
                acc = __builtin_amdgcn_mfma_f32_16x16x32_bf16(a1, xb[ic][1], acc, 0, 0, 0);
                int c = (2 * w + ic) * 16 + n16;
                uint2 st = make_uint2(packbf2(acc[0], acc[1]), packbf2(acc[2], acc[3]));
                *(uint2*)&EBUF[c * EROW + rt * 16 + q * 4] = st;
            }
        }

        // ---- issue seq1 raw loads NOW (seq0 pass only): their HBM latency
        //      hides under the rest of seq0's compute; device-wide, reads
        //      de-phase from the t=0 burst and overlap stores ----
        if (issueRaw1) {
#pragma unroll
            for (int ic = 0; ic < 2; ++ic) {
                int c = (2 * w + ic) * 16 + n16;
#pragma unroll
                for (int kc = 0; kc < 2; ++kc) {
                    const float* p1 = xs1 + c * MCH + kc * 32 + q * 8;
                    raw1[ic][kc][0] = __builtin_nontemporal_load((const f32x4*)p1);
                    raw1[ic][kc][1] = __builtin_nontemporal_load((const f32x4*)p1 + 1);
                }
            }
        }

        // ---- pass 1: two interleaved 16-chains (same-wave EBUF) ----
        float* sr_ = seg + sb * 1024;         // [r][8][64]
        float* si_ = sr_ + 512;
        {
            float sAr = 0.f, sAi = 0.f, sBr = 0.f, sBi = 0.f;
#pragma unroll
            for (int j = 0; j < 16; ++j) {
                uint eA = *(const uint*)&EBUF[(g * 32 + j     ) * EROW + 2 * n];
                uint eB = *(const uint*)&EBUF[(g * 32 + 16 + j) * EROW + 2 * n];
                float eAr = bf2f((ushort)(eA & 0xffffu)), eAi = bf2f((ushort)(eA >> 16));
                float eBr = bf2f((ushort)(eB & 0xffffu)), eBi = bf2f((ushort)(eB >> 16));
                float nAr = eAr + mr * sAr - mi * sAi;
                float nAi = eAi + mr * sAi + mi * sAr;
                float nBr = eBr + mr * sBr - mi * sBi;
                float nBi = eBi + mr * sBi + mi * sBr;
                sAr = nAr; sAi = nAi; sBr = nBr; sBi = nBi;
            }
            sr_[(2 * g    ) * 64 + n] = sAr; si_[(2 * g    ) * 64 + n] = sAi;
            sr_[(2 * g + 1) * 64 + n] = sBr; si_[(2 * g + 1) * 64 + n] = sBi;
        }

        // ---- T*X (overlaps pass1's dependent chain) ----
        f32x4 accT[4][2];
#pragma unroll
        for (int rt = 0; rt < 4; ++rt) {
#pragma unroll
            for (int ic = 0; ic < 2; ++ic) {
                f32x4 a = {0.f, 0.f, 0.f, 0.f};
                a = __builtin_amdgcn_mfma_f32_16x16x32_bf16(tf[rt][0], xb[ic][0], a, 0, 0, 0);
                a = __builtin_amdgcn_mfma_f32_16x16x32_bf16(tf[rt][1], xb[ic][1], a, 0, 0, 0);
                accT[rt][ic] = a;
            }
        }

        // ---- P build (seq0 only; ordered before Phase C by the barrier) ----
        if (buildP) {
#pragma unroll
            for (int i = 0; i < 16; ++i) {
                int j = g * 16 + i;
                float pr, pi; rp((float)(j + 1), pr, pi);
                float ur = wr * pr - wi * pi;
                float ui = wr * pi + wi * pr;
                *(uint*)(PTBL + ((j * 256 + n * 4) ^ ((uint)(j & 7) << 4))) = packbf2(ur, -ui);
            }
        }
        __syncthreads();                                 // seg[sb] (+P) ready

        // ---- exclusive seg prefix (<=7 terms) + pass 2 (2 chains) ----
        {
            float pr2 = 0.f, pi2 = 0.f;
            for (int s = 0; s < 2 * g; ++s) {
                float Er = sr_[s * 64 + n], Ei = si_[s * 64 + n];
                float nr = Er + m16r * pr2 - m16i * pi2;
                float ni = Ei + m16r * pi2 + m16i * pr2;
                pr2 = nr; pi2 = ni;
            }
            float sAr = pr2, sAi = pi2;
            float Gr = sr_[(2 * g) * 64 + n], Gi = si_[(2 * g) * 64 + n];
            float sBr = Gr + m16r * pr2 - m16i * pi2;
            float sBi = Gi + m16r * pi2 + m16i * pr2;
#pragma unroll
            for (int j = 0; j < 16; ++j) {
                uint* epA = (uint*)&EBUF[(g * 32 + j     ) * EROW + 2 * n];
                uint* epB = (uint*)&EBUF[(g * 32 + 16 + j) * EROW + 2 * n];
                uint eA = *epA, eB = *epB;
                float eAr = bf2f((ushort)(eA & 0xffffu)), eAi = bf2f((ushort)(eA >> 16));
                float eBr = bf2f((ushort)(eB & 0xffffu)), eBi = bf2f((ushort)(eB >> 16));
                *epA = packbf2(sAr, sAi);
                *epB = packbf2(sBr, sBi);
                float nAr = eAr + mr * sAr - mi * sAi;
                float nAi = eAi + mr * sAi + mi * sAr;
                float nBr = eBr + mr * sBr - mi * sBi;
                float nBi = eBi + mr * sBi + mi * sBr;
                sAr = nAr; sAi = nAi; sBr = nBr; sBi = nBi;
            }
        }

        // ---- Phase C: OUT = accT + P*SV (own-wave EBUF rows) ----
#pragma unroll
        for (int rt = 0; rt < 4; ++rt) {
            int row = rt * 16 + n16;
            bf16x8 p0 = *(const bf16x8*)(PTBL + ((row * 256       + q * 16) ^ xr));
            bf16x8 p1 = *(const bf16x8*)(PTBL + ((row * 256 +  64 + q * 16) ^ xr));
            bf16x8 p2 = *(const bf16x8*)(PTBL + ((row * 256 + 128 + q * 16) ^ xr));
            bf16x8 p3 = *(const bf16x8*)(PTBL + ((row * 256 + 192 + q * 16) ^ xr));
#pragma unroll
            for (int ic = 0; ic < 2; ++ic) {
                int c = (2 * w + ic) * 16 + n16;
                f32x4 accP = {0.f, 0.f, 0.f, 0.f};
                accP = __builtin_amdgcn_mfma_f32_16x16x32_bf16(p0,
                           *(const bf16x8*)&EBUF[c * EROW +       q * 8], accP, 0, 0, 0);
                accP = __builtin_amdgcn_mfma_f32_16x16x32_bf16(p1,
                           *(const bf16x8*)&EBUF[c * EROW +  32 + q * 8], accP, 0, 0, 0);
                accP = __builtin_amdgcn_mfma_f32_16x16x32_bf16(p2,
                           *(const bf16x8*)&EBUF[c * EROW +  64 + q * 8], accP, 0, 0, 0);
                accP = __builtin_amdgcn_mfma_f32_16x16x32_bf16(p3,
                           *(const bf16x8*)&EBUF[c * EROW +  96 + q * 8], accP, 0, 0, 0);
                f32x4 o;
                o[0] = accT[rt][ic][0] + accP[0];
                o[1] = accT[rt][ic][1] + accP[1];
                o[2] = accT[rt][ic][2] + accP[2];
                o[3] = accT[rt][ic][3] + accP[3];
                __builtin_nontemporal_store(o, (f32x4*)(op + c * MCH + rt * 16 + q * 4));
            }
        }
    };

    do_seq(xb0, 0, op0, true, true);

    // pack seq1 (loads issued during seq0; latency covered by seq0 compute)
    bf16x8 xb1[2][2];
#pragma unroll
    for (int ic = 0; ic < 2; ++ic)
#pragma unroll
        for (int kc = 0; kc < 2; ++kc)
            xb1[ic][kc] = pack_bf8(raw1[ic][kc][0], raw1[ic][kc][1]);

    do_seq(xb1, 1, op1, false, false);
}

extern "C" void kernel_launch(void* const* d_in, const int* in_sizes, int n_in,
                              void* d_out, int out_size, void* d_ws, size_t ws_size,
                              hipStream_t stream)
{
    const float* x  = (const float*)d_in[0];
    const float* Ar = (const float*)d_in[1];
    const float* Ai = (const float*)d_in[2];
    const float* C  = (const float*)d_in[3];
    const float* D  = (const float*)d_in[4];
    const float* ld = (const float*)d_in[5];
    float* out = (float*)d_out;
    (void)d_ws; (void)ws_size;               // workspace unused: tables live in LDS

    hipLaunchKernelGGL(s4d_fused, dim3(B_ * H_ / NSEQ), dim3(256), 0, stream,
                       x, Ar, Ai, C, D, ld, out);
}